// Round 10
// baseline (607.377 us; speedup 1.0000x reference)
//
#include <hip/hip_runtime.h>
#include <cmath>

#define DM   1024
#define DFF  4096
#define NH   16
#define HD   64
#define SEQ  2048
#define NB   2
#define NTOK (NB * SEQ)  // 4096

typedef __bf16 bf16;
typedef __bf16 bf16x8 __attribute__((ext_vector_type(8)));
typedef float  f32x4  __attribute__((ext_vector_type(4)));

// ---- MFMA via inline asm ----
__device__ __forceinline__ void mfma16(f32x4& acc, bf16x8 a, bf16x8 b) {
    asm("v_mfma_f32_16x16x32_bf16 %0, %1, %2, %0" : "+v"(acc) : "v"(a), "v"(b));
}
// ---- async global->LDS, 16B/lane; LDS base must be wave-uniform ----
__device__ __forceinline__ void gload16(const void* g, void* l) {
    __builtin_amdgcn_global_load_lds(
        (__attribute__((address_space(1))) void*)(void*)g,
        (__attribute__((address_space(3))) void*)l, 16, 0, 0);
}
// ---- fp32 -> (hi, lo) bf16 pair; hi+lo ~ 16-bit-mantissa accurate ----
__device__ __forceinline__ void split2(float v, bf16& h, bf16& l) {
    h = (bf16)v; l = (bf16)(v - (float)h);
}

// =======================================================================
// Weight transpose + fp32 -> split bf16:  W[K][N] -> Wth/Wtl [N][K]
// =======================================================================
__global__ __launch_bounds__(256) void transpose_convert(
    const float* __restrict__ W, bf16* __restrict__ Wth, bf16* __restrict__ Wtl,
    int K, int N) {
    __shared__ float tile[32][33];
    const int bn = blockIdx.x * 32;
    const int bk = blockIdx.y * 32;
    const int tx = threadIdx.x & 31;
    const int ty = (threadIdx.x >> 5) << 2;
#pragma unroll
    for (int i = 0; i < 4; ++i)
        tile[ty + i][tx] = W[(size_t)(bk + ty + i) * N + bn + tx];
    __syncthreads();
#pragma unroll
    for (int i = 0; i < 4; ++i) {
        const float v = tile[tx][ty + i];
        bf16 h, l; split2(v, h, l);
        Wth[(size_t)(bn + ty + i) * K + bk + tx] = h;
        Wtl[(size_t)(bn + ty + i) * K + bk + tx] = l;
    }
}

// =======================================================================
// LayerNorm, fp32 in -> split bf16 out
// =======================================================================
__global__ __launch_bounds__(256) void layernorm_kernel(
    const float* __restrict__ x, const float* __restrict__ scale,
    const float* __restrict__ bias, bf16* __restrict__ oh, bf16* __restrict__ ol) {
    const int row = blockIdx.x;
    const int t = threadIdx.x;
    const float4 v = ((const float4*)(x + (size_t)row * DM))[t];
    float s  = v.x + v.y + v.z + v.w;
    float ss = v.x * v.x + v.y * v.y + v.z * v.z + v.w * v.w;
#pragma unroll
    for (int m = 1; m < 64; m <<= 1) {
        s  += __shfl_xor(s, m);
        ss += __shfl_xor(ss, m);
    }
    __shared__ float red[2][4];
    const int w = t >> 6;
    if ((t & 63) == 0) { red[0][w] = s; red[1][w] = ss; }
    __syncthreads();
    s  = red[0][0] + red[0][1] + red[0][2] + red[0][3];
    ss = red[1][0] + red[1][1] + red[1][2] + red[1][3];
    const float mu = s * (1.0f / DM);
    const float rs = rsqrtf(ss * (1.0f / DM) - mu * mu + 1e-6f);
    const float4 sc = ((const float4*)scale)[t];
    const float4 bi = ((const float4*)bias)[t];
    const float y[4] = {(v.x - mu) * rs * sc.x + bi.x, (v.y - mu) * rs * sc.y + bi.y,
                        (v.z - mu) * rs * sc.z + bi.z, (v.w - mu) * rs * sc.w + bi.w};
#pragma unroll
    for (int i = 0; i < 4; ++i) {
        bf16 h, l; split2(y[i], h, l);
        oh[(size_t)row * DM + t * 4 + i] = h;
        ol[(size_t)row * DM + t * 4 + i] = l;
    }
}

// =======================================================================
// Split GEMM: C = (Ah+Al)[M][K] * (Bh+Bl)[N][K]^T, 128x128 tile, BK=64
// acc = Ah*Bh + Ah*Bl + Al*Bh  (Al*Bl dropped, <= 2^-18 relative)
// MODE 3: fp32 out0 = acc + bias0[n] + res[m][n]
// MODE 4: split bf16 out0(+loStride) = gelu_tanh(acc + bias0[n])
// MODE 5: fused QKV -> q(out0), k(out1), v^T [B,H,hd,S] (out2), split planes
// NEW (R10): XCD-chunked block remap — pure bijection on (brow,bcol); each
// XCD owns a contiguous swz chunk so operand panels become L2-resident
// per XCD instead of 8x HBM-refetched. Same safe class as R7/R9 attn maps.
// =======================================================================
template <int MODE>
__global__ __launch_bounds__(256) void gemm_bt(
    const bf16* __restrict__ Ah, const bf16* __restrict__ Al,
    const bf16* __restrict__ Bh, const bf16* __restrict__ Bl,
    const float* __restrict__ bias0, const float* __restrict__ bias1,
    const float* __restrict__ bias2, const float* __restrict__ res,
    void* __restrict__ out0, void* __restrict__ out1, void* __restrict__ out2,
    size_t loStride, int M, int N, int K) {
    __shared__ alignas(16) bf16 Ash[128 * 64];
    __shared__ alignas(16) bf16 Asl[128 * 64];
    __shared__ alignas(16) bf16 Bsh[128 * 64];
    __shared__ alignas(16) bf16 Bsl[128 * 64];
    const int t  = threadIdx.x;
    const int l  = t & 63;
    const int w  = t >> 6;
    const int wr = w >> 1, wc = w & 1;
    const int lg = l >> 4, lr = l & 15;
    // XCD-chunked remap (all grids have nwg % 8 == 0)
    const int nwg  = gridDim.x * gridDim.y;
    const int bidl = blockIdx.y * gridDim.x + blockIdx.x;
    const int swz  = (bidl & 7) * (nwg >> 3) + (bidl >> 3);
    const int brow = (swz / gridDim.x) * 128;
    const int bcol = (swz % gridDim.x) * 128;

    f32x4 acc[4][4] = {};

    const bf16* Abh = Ah + (size_t)brow * K;
    const bf16* Abl = Al + (size_t)brow * K;
    const bf16* Bbh = Bh + (size_t)bcol * K;
    const bf16* Bbl = Bl + (size_t)bcol * K;
    const int wb8 = (t & ~63) * 8;

    for (int kt = 0; kt < K; kt += 64) {
#pragma unroll
        for (int r = 0; r < 4; ++r) {
            const int e = (r * 256 + t) * 8;
            const int row = e >> 6, col = e & 63;
            const size_t go = (size_t)row * K + kt + col;
            gload16(Abh + go, &Ash[r * 2048 + wb8]);
            gload16(Abl + go, &Asl[r * 2048 + wb8]);
            gload16(Bbh + go, &Bsh[r * 2048 + wb8]);
            gload16(Bbl + go, &Bsl[r * 2048 + wb8]);
        }
        __syncthreads();
#pragma unroll
        for (int ks = 0; ks < 2; ++ks) {
            bf16x8 afh[4], afl[4], bfh[4], bfl[4];
#pragma unroll
            for (int mi = 0; mi < 4; ++mi) {
                const int off = (wr * 64 + mi * 16 + lr) * 64 + ks * 32 + lg * 8;
                afh[mi] = *(const bf16x8*)&Ash[off];
                afl[mi] = *(const bf16x8*)&Asl[off];
            }
#pragma unroll
            for (int ni = 0; ni < 4; ++ni) {
                const int off = (wc * 64 + ni * 16 + lr) * 64 + ks * 32 + lg * 8;
                bfh[ni] = *(const bf16x8*)&Bsh[off];
                bfl[ni] = *(const bf16x8*)&Bsl[off];
            }
#pragma unroll
            for (int mi = 0; mi < 4; ++mi)
#pragma unroll
                for (int ni = 0; ni < 4; ++ni) {
                    mfma16(acc[mi][ni], afh[mi], bfh[ni]);
                    mfma16(acc[mi][ni], afh[mi], bfl[ni]);
                    mfma16(acc[mi][ni], afl[mi], bfh[ni]);
                }
        }
        __syncthreads();
    }

    // epilogue: C/D layout col=lane&15, row=(lane>>4)*4+j  [m89]
#pragma unroll
    for (int ni = 0; ni < 4; ++ni) {
        const int col = bcol + wc * 64 + ni * 16 + lr;
        int nn = col;
        const float* bp = bias0;
        if constexpr (MODE == 5) {
            const int sub = col >> 10;
            nn = col & 1023;
            bp = (sub == 0) ? bias0 : (sub == 1 ? bias1 : bias2);
        }
        const float bval = bp[nn];
#pragma unroll
        for (int mi = 0; mi < 4; ++mi) {
#pragma unroll
            for (int j = 0; j < 4; ++j) {
                const int row = brow + wr * 64 + mi * 16 + lg * 4 + j;
                float v = acc[mi][ni][j] + bval;
                if constexpr (MODE == 3) {
                    ((float*)out0)[(size_t)row * N + col] = v + res[(size_t)row * N + col];
                } else if constexpr (MODE == 4) {
                    const float u = 0.7978845608028654f * (v + 0.044715f * v * v * v);
                    const float g = 0.5f * v * (1.0f + tanhf(u));
                    bf16 h, lo2; split2(g, h, lo2);
                    bf16* dst = (bf16*)out0;
                    dst[(size_t)row * N + col] = h;
                    dst[(size_t)row * N + col + loStride] = lo2;
                } else if constexpr (MODE == 5) {
                    const int sub = col >> 10;
                    bf16 h, lo2; split2(v, h, lo2);
                    if (sub < 2) {
                        bf16* dst = (bf16*)(sub == 0 ? out0 : out1);
                        dst[(size_t)row * DM + nn] = h;
                        dst[(size_t)row * DM + nn + loStride] = lo2;
                    } else {
                        const int bb = row >> 11, sI = row & (SEQ - 1);
                        const int hh = nn >> 6, d = nn & 63;
                        const size_t idx = (((size_t)((bb * NH + hh) * HD + d)) << 11) + sI;
                        ((bf16*)out2)[idx] = h;
                        ((bf16*)out2)[idx + loStride] = lo2;
                    }
                }
            }
        }
    }
}

// =======================================================================
// Causal flash attention, split-precision Q/K/P/V — R7-VERBATIM BODY,
// R9-verbatim mapping (complementary qt pairing + XCD-local bh).
// =======================================================================
__global__ __launch_bounds__(256) void attn_kernel(
    const bf16* __restrict__ qh, const bf16* __restrict__ ql,
    const bf16* __restrict__ kh, const bf16* __restrict__ kl,
    const bf16* __restrict__ vth, const bf16* __restrict__ vtl,
    bf16* __restrict__ oh, bf16* __restrict__ ol) {
    __shared__ alignas(16) bf16 Ksh[64 * 64], Ksl[64 * 64];
    __shared__ alignas(16) bf16 Vsh[64 * 64], Vsl[64 * 64];   // [hd][kv]
    __shared__ alignas(16) bf16 Psh[4][32 * 64], Psl[4][32 * 64];
    const int bid = blockIdx.x;                 // 0..511
    const int qtidx = (bid >> 3) & 15;
    const int qt = (bid & 256) ? (15 - qtidx) : qtidx;  // complementary pairing
    const int bh = (bid & 7) + 8 * (bid >> 7);  // head-group -> fixed XCD slot
    const int b = bh >> 4, h = bh & 15;
    const int t = threadIdx.x;
    const int w = t >> 6, l = t & 63;
    const int lg = l >> 4, lr = l & 15;
    const int qrow0 = qt * 128 + w * 32;
    const size_t tokbase = (size_t)b * SEQ;

    bf16x8 qfh[2][2], qfl[2][2];
#pragma unroll
    for (int mi = 0; mi < 2; ++mi)
#pragma unroll
        for (int ks = 0; ks < 2; ++ks) {
            const size_t off = (tokbase + qrow0 + mi * 16 + lr) * DM + h * HD + ks * 32 + lg * 8;
            qfh[mi][ks] = *(const bf16x8*)&qh[off];
            qfl[mi][ks] = *(const bf16x8*)&ql[off];
        }

    f32x4 oacc[2][4] = {};
    float mrow[2][4], lrow[2][4];
#pragma unroll
    for (int mi = 0; mi < 2; ++mi)
#pragma unroll
        for (int j = 0; j < 4; ++j) { mrow[mi][j] = -1e30f; lrow[mi][j] = 0.f; }

    const int wb8 = (t & ~63) * 8;
    const int nkv = 2 * (qt + 1);
    for (int kt = 0; kt < nkv; ++kt) {
#pragma unroll
        for (int r = 0; r < 2; ++r) {
            const int e = (r * 256 + t) * 8;
            const int rr = e >> 6, cc = e & 63;
            const size_t kg = (tokbase + kt * 64 + rr) * DM + h * HD + cc;
            const size_t vg = (((size_t)((b * NH + h) * HD + rr)) << 11) + kt * 64 + cc;
            gload16(&kh[kg], &Ksh[r * 2048 + wb8]);
            gload16(&kl[kg], &Ksl[r * 2048 + wb8]);
            gload16(&vth[vg], &Vsh[r * 2048 + wb8]);
            gload16(&vtl[vg], &Vsl[r * 2048 + wb8]);
        }
        __syncthreads();
        const bool active = (kt * 64 <= qrow0 + 31);
        if (active) {
            f32x4 sf[2][4] = {};
#pragma unroll
            for (int ks = 0; ks < 2; ++ks)
#pragma unroll
                for (int ni = 0; ni < 4; ++ni) {
                    const int off = (ni * 16 + lr) * 64 + ks * 32 + lg * 8;
                    const bf16x8 kfh = *(const bf16x8*)&Ksh[off];
                    const bf16x8 kfl = *(const bf16x8*)&Ksl[off];
#pragma unroll
                    for (int mi = 0; mi < 2; ++mi) {
                        mfma16(sf[mi][ni], qfh[mi][ks], kfh);
                        mfma16(sf[mi][ni], qfh[mi][ks], kfl);
                        mfma16(sf[mi][ni], qfl[mi][ks], kfh);
                    }
                }
#pragma unroll
            for (int mi = 0; mi < 2; ++mi)
#pragma unroll
                for (int ni = 0; ni < 4; ++ni)
#pragma unroll
                    for (int j = 0; j < 4; ++j) {
                        const float sv = sf[mi][ni][j] * 0.125f;
                        const int qg = qrow0 + mi * 16 + lg * 4 + j;
                        const int kg = kt * 64 + ni * 16 + lr;
                        sf[mi][ni][j] = (kg > qg) ? -1e30f : sv;
                    }
#pragma unroll
            for (int mi = 0; mi < 2; ++mi)
#pragma unroll
                for (int j = 0; j < 4; ++j) {
                    float pm = fmaxf(fmaxf(sf[mi][0][j], sf[mi][1][j]),
                                     fmaxf(sf[mi][2][j], sf[mi][3][j]));
#pragma unroll
                    for (int msk = 1; msk <= 8; msk <<= 1)
                        pm = fmaxf(pm, __shfl_xor(pm, msk));
                    const float mnew = fmaxf(mrow[mi][j], pm);
                    const float resc = __expf(mrow[mi][j] - mnew);
                    mrow[mi][j] = mnew;
                    float rsum = 0.f;
#pragma unroll
                    for (int ni = 0; ni < 4; ++ni) {
                        const float p = __expf(sf[mi][ni][j] - mnew);
                        sf[mi][ni][j] = p;
                        rsum += p;
                    }
#pragma unroll
                    for (int msk = 1; msk <= 8; msk <<= 1)
                        rsum += __shfl_xor(rsum, msk);
                    lrow[mi][j] = lrow[mi][j] * resc + rsum;
#pragma unroll
                    for (int di = 0; di < 4; ++di) oacc[mi][di][j] *= resc;
                }
#pragma unroll
            for (int mi = 0; mi < 2; ++mi)
#pragma unroll
                for (int ni = 0; ni < 4; ++ni)
#pragma unroll
                    for (int j = 0; j < 4; ++j) {
                        const float p = sf[mi][ni][j];
                        const int idx = (mi * 16 + lg * 4 + j) * 64 + ni * 16 + lr;
                        bf16 hh, lo2; split2(p, hh, lo2);
                        Psh[w][idx] = hh;
                        Psl[w][idx] = lo2;
                    }
#pragma unroll
            for (int ks = 0; ks < 2; ++ks) {
                bf16x8 pah[2], pal[2];
#pragma unroll
                for (int mi = 0; mi < 2; ++mi) {
                    const int off = (mi * 16 + lr) * 64 + ks * 32 + lg * 8;
                    pah[mi] = *(const bf16x8*)&Psh[w][off];
                    pal[mi] = *(const bf16x8*)&Psl[w][off];
                }
#pragma unroll
                for (int di = 0; di < 4; ++di) {
                    const int off = (di * 16 + lr) * 64 + ks * 32 + lg * 8;
                    const bf16x8 vfh = *(const bf16x8*)&Vsh[off];
                    const bf16x8 vfl = *(const bf16x8*)&Vsl[off];
#pragma unroll
                    for (int mi = 0; mi < 2; ++mi) {
                        mfma16(oacc[mi][di], pah[mi], vfh);
                        mfma16(oacc[mi][di], pah[mi], vfl);
                        mfma16(oacc[mi][di], pal[mi], vfh);
                    }
                }
            }
        }
        __syncthreads();
    }
#pragma unroll
    for (int mi = 0; mi < 2; ++mi)
#pragma unroll
        for (int j = 0; j < 4; ++j) {
            const float inv = 1.0f / lrow[mi][j];
            const int row = qrow0 + mi * 16 + lg * 4 + j;
#pragma unroll
            for (int di = 0; di < 4; ++di) {
                const float f = oacc[mi][di][j] * inv;
                bf16 hh, lo2; split2(f, hh, lo2);
                const size_t idx = (tokbase + row) * DM + h * HD + di * 16 + lr;
                oh[idx] = hh;
                ol[idx] = lo2;
            }
        }
}

// =======================================================================
extern "C" void kernel_launch(void* const* d_in, const int* in_sizes, int n_in,
                              void* d_out, int out_size, void* d_ws, size_t ws_size,
                              hipStream_t stream) {
    const float* x    = (const float*)d_in[0];
    const float* ln1s = (const float*)d_in[2];
    const float* ln1b = (const float*)d_in[3];
    const float* Wq   = (const float*)d_in[4];
    const float* bq   = (const float*)d_in[5];
    const float* Wk   = (const float*)d_in[6];
    const float* bk   = (const float*)d_in[7];
    const float* Wv   = (const float*)d_in[8];
    const float* bv   = (const float*)d_in[9];
    const float* Wo   = (const float*)d_in[10];
    const float* bo   = (const float*)d_in[11];
    const float* ln2s = (const float*)d_in[12];
    const float* ln2b = (const float*)d_in[13];
    const float* W1   = (const float*)d_in[14];
    const float* b1   = (const float*)d_in[15];
    const float* W2   = (const float*)d_in[16];
    const float* b2   = (const float*)d_in[17];
    float* out = (float*)d_out;

    const size_t M1 = (size_t)1024 * 1024;  // 1M elems
    bf16* ws = (bf16*)d_ws;
    // weights (split planes)
    bf16* Wqkv_h = ws;                 // 3M
    bf16* Wqkv_l = ws + 3 * M1;        // 3M
    bf16* Wo_h   = ws + 6 * M1;
    bf16* Wo_l   = ws + 7 * M1;
    bf16* W1_h   = ws + 8 * M1;        // 4M
    bf16* W1_l   = ws + 12 * M1;
    bf16* W2_h   = ws + 16 * M1;       // 4M
    bf16* W2_l   = ws + 20 * M1;
    // activations
    bf16*  xn_h  = ws + 24 * M1;       // 4M
    bf16*  xn_l  = ws + 28 * M1;
    float* x1    = (float*)(ws + 32 * M1);  // 4M fp32 (8M slots)
    bf16*  q_h   = ws + 40 * M1;
    bf16*  q_l   = ws + 44 * M1;
    bf16*  k_h   = ws + 48 * M1;
    bf16*  k_l   = ws + 52 * M1;
    bf16*  vt_h  = ws + 56 * M1;
    bf16*  vt_l  = ws + 60 * M1;
    bf16*  o_h   = ws + 64 * M1;
    bf16*  o_l   = ws + 68 * M1;       // ends 72M elems = 144MB
    // MLP hidden overlays q..o region (dead after O-proj)
    bf16*  h_h   = ws + 40 * M1;       // 16M
    bf16*  h_l   = ws + 56 * M1;       // 16M

    const dim3 blk(256);
    transpose_convert<<<dim3(32, 32), blk, 0, stream>>>(Wq, Wqkv_h,      Wqkv_l,      1024, 1024);
    transpose_convert<<<dim3(32, 32), blk, 0, stream>>>(Wk, Wqkv_h + M1, Wqkv_l + M1, 1024, 1024);
    transpose_convert<<<dim3(32, 32), blk, 0, stream>>>(Wv, Wqkv_h + 2*M1, Wqkv_l + 2*M1, 1024, 1024);
    transpose_convert<<<dim3(32, 32), blk, 0, stream>>>(Wo, Wo_h, Wo_l, 1024, 1024);
    transpose_convert<<<dim3(128, 32), blk, 0, stream>>>(W1, W1_h, W1_l, 1024, 4096);
    transpose_convert<<<dim3(32, 128), blk, 0, stream>>>(W2, W2_h, W2_l, 4096, 1024);

    layernorm_kernel<<<NTOK, blk, 0, stream>>>(x, ln1s, ln1b, xn_h, xn_l);

    gemm_bt<5><<<dim3(24, 32), blk, 0, stream>>>(xn_h, xn_l, Wqkv_h, Wqkv_l,
        bq, bk, bv, nullptr, q_h, k_h, vt_h, 4 * M1, NTOK, 3072, 1024);

    attn_kernel<<<512, blk, 0, stream>>>(q_h, q_l, k_h, k_l, vt_h, vt_l, o_h, o_l);

    gemm_bt<3><<<dim3(8, 32), blk, 0, stream>>>(o_h, o_l, Wo_h, Wo_l,
        bo, nullptr, nullptr, x, x1, nullptr, nullptr, 0, NTOK, 1024, 1024);

    layernorm_kernel<<<NTOK, blk, 0, stream>>>(x1, ln2s, ln2b, xn_h, xn_l);

    gemm_bt<4><<<dim3(32, 32), blk, 0, stream>>>(xn_h, xn_l, W1_h, W1_l,
        b1, nullptr, nullptr, nullptr, h_h, nullptr, nullptr, 16 * M1, NTOK, DFF, 1024);

    gemm_bt<3><<<dim3(8, 32), blk, 0, stream>>>(h_h, h_l, W2_h, W2_l,
        b2, nullptr, nullptr, x1, out, nullptr, nullptr, 0, NTOK, 1024, DFF);
}

// Round 11
// 553.223 us; speedup vs baseline: 1.0979x; 1.0979x over previous
//
#include <hip/hip_runtime.h>
#include <cmath>

#define DM   1024
#define DFF  4096
#define NH   16
#define HD   64
#define SEQ  2048
#define NB   2
#define NTOK (NB * SEQ)  // 4096

typedef __bf16 bf16;
typedef __bf16 bf16x8 __attribute__((ext_vector_type(8)));
typedef float  f32x4  __attribute__((ext_vector_type(4)));

// ---- MFMA via inline asm ----
__device__ __forceinline__ void mfma16(f32x4& acc, bf16x8 a, bf16x8 b) {
    asm("v_mfma_f32_16x16x32_bf16 %0, %1, %2, %0" : "+v"(acc) : "v"(a), "v"(b));
}
// ---- async global->LDS, 16B/lane; LDS base must be wave-uniform ----
__device__ __forceinline__ void gload16(const void* g, void* l) {
    __builtin_amdgcn_global_load_lds(
        (__attribute__((address_space(1))) void*)(void*)g,
        (__attribute__((address_space(3))) void*)l, 16, 0, 0);
}
// ---- fp32 -> (hi, lo) bf16 pair; hi+lo ~ 16-bit-mantissa accurate ----
__device__ __forceinline__ void split2(float v, bf16& h, bf16& l) {
    h = (bf16)v; l = (bf16)(v - (float)h);
}

// =======================================================================
// Weight transpose + fp32 -> split bf16:  W[K][N] -> Wth/Wtl [N][K]
// =======================================================================
__global__ __launch_bounds__(256) void transpose_convert(
    const float* __restrict__ W, bf16* __restrict__ Wth, bf16* __restrict__ Wtl,
    int K, int N) {
    __shared__ float tile[32][33];
    const int bn = blockIdx.x * 32;
    const int bk = blockIdx.y * 32;
    const int tx = threadIdx.x & 31;
    const int ty = (threadIdx.x >> 5) << 2;
#pragma unroll
    for (int i = 0; i < 4; ++i)
        tile[ty + i][tx] = W[(size_t)(bk + ty + i) * N + bn + tx];
    __syncthreads();
#pragma unroll
    for (int i = 0; i < 4; ++i) {
        const float v = tile[tx][ty + i];
        bf16 h, l; split2(v, h, l);
        Wth[(size_t)(bn + ty + i) * K + bk + tx] = h;
        Wtl[(size_t)(bn + ty + i) * K + bk + tx] = l;
    }
}

// =======================================================================
// LayerNorm, fp32 in -> split bf16 out
// =======================================================================
__global__ __launch_bounds__(256) void layernorm_kernel(
    const float* __restrict__ x, const float* __restrict__ scale,
    const float* __restrict__ bias, bf16* __restrict__ oh, bf16* __restrict__ ol) {
    const int row = blockIdx.x;
    const int t = threadIdx.x;
    const float4 v = ((const float4*)(x + (size_t)row * DM))[t];
    float s  = v.x + v.y + v.z + v.w;
    float ss = v.x * v.x + v.y * v.y + v.z * v.z + v.w * v.w;
#pragma unroll
    for (int m = 1; m < 64; m <<= 1) {
        s  += __shfl_xor(s, m);
        ss += __shfl_xor(ss, m);
    }
    __shared__ float red[2][4];
    const int w = t >> 6;
    if ((t & 63) == 0) { red[0][w] = s; red[1][w] = ss; }
    __syncthreads();
    s  = red[0][0] + red[0][1] + red[0][2] + red[0][3];
    ss = red[1][0] + red[1][1] + red[1][2] + red[1][3];
    const float mu = s * (1.0f / DM);
    const float rs = rsqrtf(ss * (1.0f / DM) - mu * mu + 1e-6f);
    const float4 sc = ((const float4*)scale)[t];
    const float4 bi = ((const float4*)bias)[t];
    const float y[4] = {(v.x - mu) * rs * sc.x + bi.x, (v.y - mu) * rs * sc.y + bi.y,
                        (v.z - mu) * rs * sc.z + bi.z, (v.w - mu) * rs * sc.w + bi.w};
#pragma unroll
    for (int i = 0; i < 4; ++i) {
        bf16 h, l; split2(y[i], h, l);
        oh[(size_t)row * DM + t * 4 + i] = h;
        ol[(size_t)row * DM + t * 4 + i] = l;
    }
}

// =======================================================================
// Split GEMM (R10-verbatim): C = (Ah+Al)[M][K] * (Bh+Bl)[N][K]^T
// acc = Ah*Bh + Ah*Bl + Al*Bh.  128x128 tile, BK=64, XCD-chunked remap.
// MODE 3: fp32 out0 = acc + bias0[n] + res[m][n]
// MODE 5: fused QKV -> q(out0), k(out1), v^T [B,H,hd,S] (out2), split planes
// =======================================================================
template <int MODE>
__global__ __launch_bounds__(256) void gemm_bt(
    const bf16* __restrict__ Ah, const bf16* __restrict__ Al,
    const bf16* __restrict__ Bh, const bf16* __restrict__ Bl,
    const float* __restrict__ bias0, const float* __restrict__ bias1,
    const float* __restrict__ bias2, const float* __restrict__ res,
    void* __restrict__ out0, void* __restrict__ out1, void* __restrict__ out2,
    size_t loStride, int M, int N, int K) {
    __shared__ alignas(16) bf16 Ash[128 * 64];
    __shared__ alignas(16) bf16 Asl[128 * 64];
    __shared__ alignas(16) bf16 Bsh[128 * 64];
    __shared__ alignas(16) bf16 Bsl[128 * 64];
    const int t  = threadIdx.x;
    const int l  = t & 63;
    const int w  = t >> 6;
    const int wr = w >> 1, wc = w & 1;
    const int lg = l >> 4, lr = l & 15;
    // XCD-chunked remap (all grids have nwg % 8 == 0)
    const int nwg  = gridDim.x * gridDim.y;
    const int bidl = blockIdx.y * gridDim.x + blockIdx.x;
    const int swz  = (bidl & 7) * (nwg >> 3) + (bidl >> 3);
    const int brow = (swz / gridDim.x) * 128;
    const int bcol = (swz % gridDim.x) * 128;

    f32x4 acc[4][4] = {};

    const bf16* Abh = Ah + (size_t)brow * K;
    const bf16* Abl = Al + (size_t)brow * K;
    const bf16* Bbh = Bh + (size_t)bcol * K;
    const bf16* Bbl = Bl + (size_t)bcol * K;
    const int wb8 = (t & ~63) * 8;

    for (int kt = 0; kt < K; kt += 64) {
#pragma unroll
        for (int r = 0; r < 4; ++r) {
            const int e = (r * 256 + t) * 8;
            const int row = e >> 6, col = e & 63;
            const size_t go = (size_t)row * K + kt + col;
            gload16(Abh + go, &Ash[r * 2048 + wb8]);
            gload16(Abl + go, &Asl[r * 2048 + wb8]);
            gload16(Bbh + go, &Bsh[r * 2048 + wb8]);
            gload16(Bbl + go, &Bsl[r * 2048 + wb8]);
        }
        __syncthreads();
#pragma unroll
        for (int ks = 0; ks < 2; ++ks) {
            bf16x8 afh[4], afl[4], bfh[4], bfl[4];
#pragma unroll
            for (int mi = 0; mi < 4; ++mi) {
                const int off = (wr * 64 + mi * 16 + lr) * 64 + ks * 32 + lg * 8;
                afh[mi] = *(const bf16x8*)&Ash[off];
                afl[mi] = *(const bf16x8*)&Asl[off];
            }
#pragma unroll
            for (int ni = 0; ni < 4; ++ni) {
                const int off = (wc * 64 + ni * 16 + lr) * 64 + ks * 32 + lg * 8;
                bfh[ni] = *(const bf16x8*)&Bsh[off];
                bfl[ni] = *(const bf16x8*)&Bsl[off];
            }
#pragma unroll
            for (int mi = 0; mi < 4; ++mi)
#pragma unroll
                for (int ni = 0; ni < 4; ++ni) {
                    mfma16(acc[mi][ni], afh[mi], bfh[ni]);
                    mfma16(acc[mi][ni], afh[mi], bfl[ni]);
                    mfma16(acc[mi][ni], afl[mi], bfh[ni]);
                }
        }
        __syncthreads();
    }

    // epilogue: C/D layout col=lane&15, row=(lane>>4)*4+j  [m89]
#pragma unroll
    for (int ni = 0; ni < 4; ++ni) {
        const int col = bcol + wc * 64 + ni * 16 + lr;
        int nn = col;
        const float* bp = bias0;
        if constexpr (MODE == 5) {
            const int sub = col >> 10;
            nn = col & 1023;
            bp = (sub == 0) ? bias0 : (sub == 1 ? bias1 : bias2);
        }
        const float bval = bp[nn];
#pragma unroll
        for (int mi = 0; mi < 4; ++mi) {
#pragma unroll
            for (int j = 0; j < 4; ++j) {
                const int row = brow + wr * 64 + mi * 16 + lg * 4 + j;
                float v = acc[mi][ni][j] + bval;
                if constexpr (MODE == 3) {
                    ((float*)out0)[(size_t)row * N + col] = v + res[(size_t)row * N + col];
                } else if constexpr (MODE == 5) {
                    const int sub = col >> 10;
                    bf16 h, lo2; split2(v, h, lo2);
                    if (sub < 2) {
                        bf16* dst = (bf16*)(sub == 0 ? out0 : out1);
                        dst[(size_t)row * DM + nn] = h;
                        dst[(size_t)row * DM + nn + loStride] = lo2;
                    } else {
                        const int bb = row >> 11, sI = row & (SEQ - 1);
                        const int hh = nn >> 6, d = nn & 63;
                        const size_t idx = (((size_t)((bb * NH + hh) * HD + d)) << 11) + sI;
                        ((bf16*)out2)[idx] = h;
                        ((bf16*)out2)[idx + loStride] = lo2;
                    }
                }
            }
        }
    }
}

// =======================================================================
// gemm_bt2: literal copy of gemm_bt with the A-lo plane deleted.
// C = Ah[M][K] * (Bh+Bl)[N][K]^T;  acc = Ah*Bh + Ah*Bl.
// LDS 48KB (3 buffers) -> 3 blocks/CU. Used for the two MLP GEMMs where
// the activation-lo term is < 2^-9 relative (error budget analysis R11).
// MODE 3: fp32 out0 = acc + bias0[n] + res[m][n]
// MODE 4: bf16 out0 = gelu_tanh(acc + bias0[n])  (hi plane only)
// =======================================================================
template <int MODE>
__global__ __launch_bounds__(256) void gemm_bt2(
    const bf16* __restrict__ Ah,
    const bf16* __restrict__ Bh, const bf16* __restrict__ Bl,
    const float* __restrict__ bias0, const float* __restrict__ res,
    void* __restrict__ out0, int M, int N, int K) {
    __shared__ alignas(16) bf16 Ash[128 * 64];
    __shared__ alignas(16) bf16 Bsh[128 * 64];
    __shared__ alignas(16) bf16 Bsl[128 * 64];
    const int t  = threadIdx.x;
    const int l  = t & 63;
    const int w  = t >> 6;
    const int wr = w >> 1, wc = w & 1;
    const int lg = l >> 4, lr = l & 15;
    // XCD-chunked remap (all grids have nwg % 8 == 0)
    const int nwg  = gridDim.x * gridDim.y;
    const int bidl = blockIdx.y * gridDim.x + blockIdx.x;
    const int swz  = (bidl & 7) * (nwg >> 3) + (bidl >> 3);
    const int brow = (swz / gridDim.x) * 128;
    const int bcol = (swz % gridDim.x) * 128;

    f32x4 acc[4][4] = {};

    const bf16* Abh = Ah + (size_t)brow * K;
    const bf16* Bbh = Bh + (size_t)bcol * K;
    const bf16* Bbl = Bl + (size_t)bcol * K;
    const int wb8 = (t & ~63) * 8;

    for (int kt = 0; kt < K; kt += 64) {
#pragma unroll
        for (int r = 0; r < 4; ++r) {
            const int e = (r * 256 + t) * 8;
            const int row = e >> 6, col = e & 63;
            const size_t go = (size_t)row * K + kt + col;
            gload16(Abh + go, &Ash[r * 2048 + wb8]);
            gload16(Bbh + go, &Bsh[r * 2048 + wb8]);
            gload16(Bbl + go, &Bsl[r * 2048 + wb8]);
        }
        __syncthreads();
#pragma unroll
        for (int ks = 0; ks < 2; ++ks) {
            bf16x8 afh[4], bfh[4], bfl[4];
#pragma unroll
            for (int mi = 0; mi < 4; ++mi) {
                const int off = (wr * 64 + mi * 16 + lr) * 64 + ks * 32 + lg * 8;
                afh[mi] = *(const bf16x8*)&Ash[off];
            }
#pragma unroll
            for (int ni = 0; ni < 4; ++ni) {
                const int off = (wc * 64 + ni * 16 + lr) * 64 + ks * 32 + lg * 8;
                bfh[ni] = *(const bf16x8*)&Bsh[off];
                bfl[ni] = *(const bf16x8*)&Bsl[off];
            }
#pragma unroll
            for (int mi = 0; mi < 4; ++mi)
#pragma unroll
                for (int ni = 0; ni < 4; ++ni) {
                    mfma16(acc[mi][ni], afh[mi], bfh[ni]);
                    mfma16(acc[mi][ni], afh[mi], bfl[ni]);
                }
        }
        __syncthreads();
    }

    // epilogue: C/D layout col=lane&15, row=(lane>>4)*4+j  [m89]
#pragma unroll
    for (int ni = 0; ni < 4; ++ni) {
        const int col = bcol + wc * 64 + ni * 16 + lr;
        const float bval = bias0[col];
#pragma unroll
        for (int mi = 0; mi < 4; ++mi) {
#pragma unroll
            for (int j = 0; j < 4; ++j) {
                const int row = brow + wr * 64 + mi * 16 + lg * 4 + j;
                float v = acc[mi][ni][j] + bval;
                if constexpr (MODE == 3) {
                    ((float*)out0)[(size_t)row * N + col] = v + res[(size_t)row * N + col];
                } else if constexpr (MODE == 4) {
                    const float u = 0.7978845608028654f * (v + 0.044715f * v * v * v);
                    const float g = 0.5f * v * (1.0f + tanhf(u));
                    ((bf16*)out0)[(size_t)row * N + col] = (bf16)g;
                }
            }
        }
    }
}

// =======================================================================
// Causal flash attention, split-precision Q/K/P/V — R7-VERBATIM BODY,
// R9-verbatim mapping (complementary qt pairing + XCD-local bh).
// =======================================================================
__global__ __launch_bounds__(256) void attn_kernel(
    const bf16* __restrict__ qh, const bf16* __restrict__ ql,
    const bf16* __restrict__ kh, const bf16* __restrict__ kl,
    const bf16* __restrict__ vth, const bf16* __restrict__ vtl,
    bf16* __restrict__ oh, bf16* __restrict__ ol) {
    __shared__ alignas(16) bf16 Ksh[64 * 64], Ksl[64 * 64];
    __shared__ alignas(16) bf16 Vsh[64 * 64], Vsl[64 * 64];   // [hd][kv]
    __shared__ alignas(16) bf16 Psh[4][32 * 64], Psl[4][32 * 64];
    const int bid = blockIdx.x;                 // 0..511
    const int qtidx = (bid >> 3) & 15;
    const int qt = (bid & 256) ? (15 - qtidx) : qtidx;  // complementary pairing
    const int bh = (bid & 7) + 8 * (bid >> 7);  // head-group -> fixed XCD slot
    const int b = bh >> 4, h = bh & 15;
    const int t = threadIdx.x;
    const int w = t >> 6, l = t & 63;
    const int lg = l >> 4, lr = l & 15;
    const int qrow0 = qt * 128 + w * 32;
    const size_t tokbase = (size_t)b * SEQ;

    bf16x8 qfh[2][2], qfl[2][2];
#pragma unroll
    for (int mi = 0; mi < 2; ++mi)
#pragma unroll
        for (int ks = 0; ks < 2; ++ks) {
            const size_t off = (tokbase + qrow0 + mi * 16 + lr) * DM + h * HD + ks * 32 + lg * 8;
            qfh[mi][ks] = *(const bf16x8*)&qh[off];
            qfl[mi][ks] = *(const bf16x8*)&ql[off];
        }

    f32x4 oacc[2][4] = {};
    float mrow[2][4], lrow[2][4];
#pragma unroll
    for (int mi = 0; mi < 2; ++mi)
#pragma unroll
        for (int j = 0; j < 4; ++j) { mrow[mi][j] = -1e30f; lrow[mi][j] = 0.f; }

    const int wb8 = (t & ~63) * 8;
    const int nkv = 2 * (qt + 1);
    for (int kt = 0; kt < nkv; ++kt) {
#pragma unroll
        for (int r = 0; r < 2; ++r) {
            const int e = (r * 256 + t) * 8;
            const int rr = e >> 6, cc = e & 63;
            const size_t kg = (tokbase + kt * 64 + rr) * DM + h * HD + cc;
            const size_t vg = (((size_t)((b * NH + h) * HD + rr)) << 11) + kt * 64 + cc;
            gload16(&kh[kg], &Ksh[r * 2048 + wb8]);
            gload16(&kl[kg], &Ksl[r * 2048 + wb8]);
            gload16(&vth[vg], &Vsh[r * 2048 + wb8]);
            gload16(&vtl[vg], &Vsl[r * 2048 + wb8]);
        }
        __syncthreads();
        const bool active = (kt * 64 <= qrow0 + 31);
        if (active) {
            f32x4 sf[2][4] = {};
#pragma unroll
            for (int ks = 0; ks < 2; ++ks)
#pragma unroll
                for (int ni = 0; ni < 4; ++ni) {
                    const int off = (ni * 16 + lr) * 64 + ks * 32 + lg * 8;
                    const bf16x8 kfh = *(const bf16x8*)&Ksh[off];
                    const bf16x8 kfl = *(const bf16x8*)&Ksl[off];
#pragma unroll
                    for (int mi = 0; mi < 2; ++mi) {
                        mfma16(sf[mi][ni], qfh[mi][ks], kfh);
                        mfma16(sf[mi][ni], qfh[mi][ks], kfl);
                        mfma16(sf[mi][ni], qfl[mi][ks], kfh);
                    }
                }
#pragma unroll
            for (int mi = 0; mi < 2; ++mi)
#pragma unroll
                for (int ni = 0; ni < 4; ++ni)
#pragma unroll
                    for (int j = 0; j < 4; ++j) {
                        const float sv = sf[mi][ni][j] * 0.125f;
                        const int qg = qrow0 + mi * 16 + lg * 4 + j;
                        const int kg = kt * 64 + ni * 16 + lr;
                        sf[mi][ni][j] = (kg > qg) ? -1e30f : sv;
                    }
#pragma unroll
            for (int mi = 0; mi < 2; ++mi)
#pragma unroll
                for (int j = 0; j < 4; ++j) {
                    float pm = fmaxf(fmaxf(sf[mi][0][j], sf[mi][1][j]),
                                     fmaxf(sf[mi][2][j], sf[mi][3][j]));
#pragma unroll
                    for (int msk = 1; msk <= 8; msk <<= 1)
                        pm = fmaxf(pm, __shfl_xor(pm, msk));
                    const float mnew = fmaxf(mrow[mi][j], pm);
                    const float resc = __expf(mrow[mi][j] - mnew);
                    mrow[mi][j] = mnew;
                    float rsum = 0.f;
#pragma unroll
                    for (int ni = 0; ni < 4; ++ni) {
                        const float p = __expf(sf[mi][ni][j] - mnew);
                        sf[mi][ni][j] = p;
                        rsum += p;
                    }
#pragma unroll
                    for (int msk = 1; msk <= 8; msk <<= 1)
                        rsum += __shfl_xor(rsum, msk);
                    lrow[mi][j] = lrow[mi][j] * resc + rsum;
#pragma unroll
                    for (int di = 0; di < 4; ++di) oacc[mi][di][j] *= resc;
                }
#pragma unroll
            for (int mi = 0; mi < 2; ++mi)
#pragma unroll
                for (int ni = 0; ni < 4; ++ni)
#pragma unroll
                    for (int j = 0; j < 4; ++j) {
                        const float p = sf[mi][ni][j];
                        const int idx = (mi * 16 + lg * 4 + j) * 64 + ni * 16 + lr;
                        bf16 hh, lo2; split2(p, hh, lo2);
                        Psh[w][idx] = hh;
                        Psl[w][idx] = lo2;
                    }
#pragma unroll
            for (int ks = 0; ks < 2; ++ks) {
                bf16x8 pah[2], pal[2];
#pragma unroll
                for (int mi = 0; mi < 2; ++mi) {
                    const int off = (mi * 16 + lr) * 64 + ks * 32 + lg * 8;
                    pah[mi] = *(const bf16x8*)&Psh[w][off];
                    pal[mi] = *(const bf16x8*)&Psl[w][off];
                }
#pragma unroll
                for (int di = 0; di < 4; ++di) {
                    const int off = (di * 16 + lr) * 64 + ks * 32 + lg * 8;
                    const bf16x8 vfh = *(const bf16x8*)&Vsh[off];
                    const bf16x8 vfl = *(const bf16x8*)&Vsl[off];
#pragma unroll
                    for (int mi = 0; mi < 2; ++mi) {
                        mfma16(oacc[mi][di], pah[mi], vfh);
                        mfma16(oacc[mi][di], pah[mi], vfl);
                        mfma16(oacc[mi][di], pal[mi], vfh);
                    }
                }
            }
        }
        __syncthreads();
    }
#pragma unroll
    for (int mi = 0; mi < 2; ++mi)
#pragma unroll
        for (int j = 0; j < 4; ++j) {
            const float inv = 1.0f / lrow[mi][j];
            const int row = qrow0 + mi * 16 + lg * 4 + j;
#pragma unroll
            for (int di = 0; di < 4; ++di) {
                const float f = oacc[mi][di][j] * inv;
                bf16 hh, lo2; split2(f, hh, lo2);
                const size_t idx = (tokbase + row) * DM + h * HD + di * 16 + lr;
                oh[idx] = hh;
                ol[idx] = lo2;
            }
        }
}

// =======================================================================
extern "C" void kernel_launch(void* const* d_in, const int* in_sizes, int n_in,
                              void* d_out, int out_size, void* d_ws, size_t ws_size,
                              hipStream_t stream) {
    const float* x    = (const float*)d_in[0];
    const float* ln1s = (const float*)d_in[2];
    const float* ln1b = (const float*)d_in[3];
    const float* Wq   = (const float*)d_in[4];
    const float* bq   = (const float*)d_in[5];
    const float* Wk   = (const float*)d_in[6];
    const float* bk   = (const float*)d_in[7];
    const float* Wv   = (const float*)d_in[8];
    const float* bv   = (const float*)d_in[9];
    const float* Wo   = (const float*)d_in[10];
    const float* bo   = (const float*)d_in[11];
    const float* ln2s = (const float*)d_in[12];
    const float* ln2b = (const float*)d_in[13];
    const float* W1   = (const float*)d_in[14];
    const float* b1   = (const float*)d_in[15];
    const float* W2   = (const float*)d_in[16];
    const float* b2   = (const float*)d_in[17];
    float* out = (float*)d_out;

    const size_t M1 = (size_t)1024 * 1024;  // 1M elems
    bf16* ws = (bf16*)d_ws;
    // weights (split planes)
    bf16* Wqkv_h = ws;                 // 3M
    bf16* Wqkv_l = ws + 3 * M1;        // 3M
    bf16* Wo_h   = ws + 6 * M1;
    bf16* Wo_l   = ws + 7 * M1;
    bf16* W1_h   = ws + 8 * M1;        // 4M
    bf16* W1_l   = ws + 12 * M1;
    bf16* W2_h   = ws + 16 * M1;       // 4M
    bf16* W2_l   = ws + 20 * M1;
    // activations
    bf16*  xn_h  = ws + 24 * M1;       // 4M
    bf16*  xn_l  = ws + 28 * M1;
    float* x1    = (float*)(ws + 32 * M1);  // 4M fp32 (8M slots)
    bf16*  q_h   = ws + 40 * M1;
    bf16*  q_l   = ws + 44 * M1;
    bf16*  k_h   = ws + 48 * M1;
    bf16*  k_l   = ws + 52 * M1;
    bf16*  vt_h  = ws + 56 * M1;
    bf16*  vt_l  = ws + 60 * M1;
    bf16*  o_h   = ws + 64 * M1;
    bf16*  o_l   = ws + 68 * M1;       // ends 72M elems = 144MB
    // MLP hidden (hi only now) overlays q..o region (dead after O-proj)
    bf16*  h_h   = ws + 40 * M1;       // 16M

    const dim3 blk(256);
    transpose_convert<<<dim3(32, 32), blk, 0, stream>>>(Wq, Wqkv_h,      Wqkv_l,      1024, 1024);
    transpose_convert<<<dim3(32, 32), blk, 0, stream>>>(Wk, Wqkv_h + M1, Wqkv_l + M1, 1024, 1024);
    transpose_convert<<<dim3(32, 32), blk, 0, stream>>>(Wv, Wqkv_h + 2*M1, Wqkv_l + 2*M1, 1024, 1024);
    transpose_convert<<<dim3(32, 32), blk, 0, stream>>>(Wo, Wo_h, Wo_l, 1024, 1024);
    transpose_convert<<<dim3(128, 32), blk, 0, stream>>>(W1, W1_h, W1_l, 1024, 4096);
    transpose_convert<<<dim3(32, 128), blk, 0, stream>>>(W2, W2_h, W2_l, 4096, 1024);

    layernorm_kernel<<<NTOK, blk, 0, stream>>>(x, ln1s, ln1b, xn_h, xn_l);

    gemm_bt<5><<<dim3(24, 32), blk, 0, stream>>>(xn_h, xn_l, Wqkv_h, Wqkv_l,
        bq, bk, bv, nullptr, q_h, k_h, vt_h, 4 * M1, NTOK, 3072, 1024);

    attn_kernel<<<512, blk, 0, stream>>>(q_h, q_l, k_h, k_l, vt_h, vt_l, o_h, o_l);

    gemm_bt<3><<<dim3(8, 32), blk, 0, stream>>>(o_h, o_l, Wo_h, Wo_l,
        bo, nullptr, nullptr, x, x1, nullptr, nullptr, 0, NTOK, 1024, 1024);

    layernorm_kernel<<<NTOK, blk, 0, stream>>>(x1, ln2s, ln2b, xn_h, xn_l);

    // MLP up + GELU (A hi-only x split W1 -> bf16 h, hi plane)
    gemm_bt2<4><<<dim3(32, 32), blk, 0, stream>>>(xn_h, W1_h, W1_l,
        b1, nullptr, h_h, NTOK, DFF, 1024);

    // MLP down + residual -> out (A hi-only x split W2)
    gemm_bt2<3><<<dim3(8, 32), blk, 0, stream>>>(h_h, W2_h, W2_l,
        b2, x1, out, NTOK, 1024, DFF);
}

// Round 13
// 509.813 us; speedup vs baseline: 1.1914x; 1.0851x over previous
//
#include <hip/hip_runtime.h>
#include <cmath>

#define DM   1024
#define DFF  4096
#define NH   16
#define HD   64
#define SEQ  2048
#define NB   2
#define NTOK (NB * SEQ)  // 4096

typedef __bf16 bf16;
typedef __bf16 bf16x8 __attribute__((ext_vector_type(8)));
typedef float  f32x4  __attribute__((ext_vector_type(4)));

// ---- MFMA via inline asm ----
__device__ __forceinline__ void mfma16(f32x4& acc, bf16x8 a, bf16x8 b) {
    asm("v_mfma_f32_16x16x32_bf16 %0, %1, %2, %0" : "+v"(acc) : "v"(a), "v"(b));
}
// ---- async global->LDS, 16B/lane; LDS base must be wave-uniform ----
__device__ __forceinline__ void gload16(const void* g, void* l) {
    __builtin_amdgcn_global_load_lds(
        (__attribute__((address_space(1))) void*)(void*)g,
        (__attribute__((address_space(3))) void*)l, 16, 0, 0);
}
// ---- fp32 -> (hi, lo) bf16 pair; hi+lo ~ 16-bit-mantissa accurate ----
__device__ __forceinline__ void split2(float v, bf16& h, bf16& l) {
    h = (bf16)v; l = (bf16)(v - (float)h);
}

// =======================================================================
// Weight transpose + fp32 -> split bf16:  W[K][N] -> Wth/Wtl [N][K]
// =======================================================================
__global__ __launch_bounds__(256) void transpose_convert(
    const float* __restrict__ W, bf16* __restrict__ Wth, bf16* __restrict__ Wtl,
    int K, int N) {
    __shared__ float tile[32][33];
    const int bn = blockIdx.x * 32;
    const int bk = blockIdx.y * 32;
    const int tx = threadIdx.x & 31;
    const int ty = (threadIdx.x >> 5) << 2;
#pragma unroll
    for (int i = 0; i < 4; ++i)
        tile[ty + i][tx] = W[(size_t)(bk + ty + i) * N + bn + tx];
    __syncthreads();
#pragma unroll
    for (int i = 0; i < 4; ++i) {
        const float v = tile[tx][ty + i];
        bf16 h, l; split2(v, h, l);
        Wth[(size_t)(bn + ty + i) * K + bk + tx] = h;
        Wtl[(size_t)(bn + ty + i) * K + bk + tx] = l;
    }
}

// =======================================================================
// LayerNorm, fp32 in -> split bf16 out
// =======================================================================
__global__ __launch_bounds__(256) void layernorm_kernel(
    const float* __restrict__ x, const float* __restrict__ scale,
    const float* __restrict__ bias, bf16* __restrict__ oh, bf16* __restrict__ ol) {
    const int row = blockIdx.x;
    const int t = threadIdx.x;
    const float4 v = ((const float4*)(x + (size_t)row * DM))[t];
    float s  = v.x + v.y + v.z + v.w;
    float ss = v.x * v.x + v.y * v.y + v.z * v.z + v.w * v.w;
#pragma unroll
    for (int m = 1; m < 64; m <<= 1) {
        s  += __shfl_xor(s, m);
        ss += __shfl_xor(ss, m);
    }
    __shared__ float red[2][4];
    const int w = t >> 6;
    if ((t & 63) == 0) { red[0][w] = s; red[1][w] = ss; }
    __syncthreads();
    s  = red[0][0] + red[0][1] + red[0][2] + red[0][3];
    ss = red[1][0] + red[1][1] + red[1][2] + red[1][3];
    const float mu = s * (1.0f / DM);
    const float rs = rsqrtf(ss * (1.0f / DM) - mu * mu + 1e-6f);
    const float4 sc = ((const float4*)scale)[t];
    const float4 bi = ((const float4*)bias)[t];
    const float y[4] = {(v.x - mu) * rs * sc.x + bi.x, (v.y - mu) * rs * sc.y + bi.y,
                        (v.z - mu) * rs * sc.z + bi.z, (v.w - mu) * rs * sc.w + bi.w};
#pragma unroll
    for (int i = 0; i < 4; ++i) {
        bf16 h, l; split2(y[i], h, l);
        oh[(size_t)row * DM + t * 4 + i] = h;
        ol[(size_t)row * DM + t * 4 + i] = l;
    }
}

// =======================================================================
// Split GEMM (R10-verbatim): C = (Ah+Al)[M][K] * (Bh+Bl)[N][K]^T
// acc = Ah*Bh + Ah*Bl + Al*Bh.  128x128 tile, BK=64, XCD-chunked remap.
// MODE 3: fp32 out0 = acc + bias0[n] + res[m][n]
// MODE 5: fused QKV -> q(out0), k(out1), v^T [B,H,hd,S] (out2), split planes
// =======================================================================
template <int MODE>
__global__ __launch_bounds__(256) void gemm_bt(
    const bf16* __restrict__ Ah, const bf16* __restrict__ Al,
    const bf16* __restrict__ Bh, const bf16* __restrict__ Bl,
    const float* __restrict__ bias0, const float* __restrict__ bias1,
    const float* __restrict__ bias2, const float* __restrict__ res,
    void* __restrict__ out0, void* __restrict__ out1, void* __restrict__ out2,
    size_t loStride, int M, int N, int K) {
    __shared__ alignas(16) bf16 Ash[128 * 64];
    __shared__ alignas(16) bf16 Asl[128 * 64];
    __shared__ alignas(16) bf16 Bsh[128 * 64];
    __shared__ alignas(16) bf16 Bsl[128 * 64];
    const int t  = threadIdx.x;
    const int l  = t & 63;
    const int w  = t >> 6;
    const int wr = w >> 1, wc = w & 1;
    const int lg = l >> 4, lr = l & 15;
    // XCD-chunked remap (all grids have nwg % 8 == 0)
    const int nwg  = gridDim.x * gridDim.y;
    const int bidl = blockIdx.y * gridDim.x + blockIdx.x;
    const int swz  = (bidl & 7) * (nwg >> 3) + (bidl >> 3);
    const int brow = (swz / gridDim.x) * 128;
    const int bcol = (swz % gridDim.x) * 128;

    f32x4 acc[4][4] = {};

    const bf16* Abh = Ah + (size_t)brow * K;
    const bf16* Abl = Al + (size_t)brow * K;
    const bf16* Bbh = Bh + (size_t)bcol * K;
    const bf16* Bbl = Bl + (size_t)bcol * K;
    const int wb8 = (t & ~63) * 8;

    for (int kt = 0; kt < K; kt += 64) {
#pragma unroll
        for (int r = 0; r < 4; ++r) {
            const int e = (r * 256 + t) * 8;
            const int row = e >> 6, col = e & 63;
            const size_t go = (size_t)row * K + kt + col;
            gload16(Abh + go, &Ash[r * 2048 + wb8]);
            gload16(Abl + go, &Asl[r * 2048 + wb8]);
            gload16(Bbh + go, &Bsh[r * 2048 + wb8]);
            gload16(Bbl + go, &Bsl[r * 2048 + wb8]);
        }
        __syncthreads();
#pragma unroll
        for (int ks = 0; ks < 2; ++ks) {
            bf16x8 afh[4], afl[4], bfh[4], bfl[4];
#pragma unroll
            for (int mi = 0; mi < 4; ++mi) {
                const int off = (wr * 64 + mi * 16 + lr) * 64 + ks * 32 + lg * 8;
                afh[mi] = *(const bf16x8*)&Ash[off];
                afl[mi] = *(const bf16x8*)&Asl[off];
            }
#pragma unroll
            for (int ni = 0; ni < 4; ++ni) {
                const int off = (wc * 64 + ni * 16 + lr) * 64 + ks * 32 + lg * 8;
                bfh[ni] = *(const bf16x8*)&Bsh[off];
                bfl[ni] = *(const bf16x8*)&Bsl[off];
            }
#pragma unroll
            for (int mi = 0; mi < 4; ++mi)
#pragma unroll
                for (int ni = 0; ni < 4; ++ni) {
                    mfma16(acc[mi][ni], afh[mi], bfh[ni]);
                    mfma16(acc[mi][ni], afh[mi], bfl[ni]);
                    mfma16(acc[mi][ni], afl[mi], bfh[ni]);
                }
        }
        __syncthreads();
    }

    // epilogue: C/D layout col=lane&15, row=(lane>>4)*4+j  [m89]
#pragma unroll
    for (int ni = 0; ni < 4; ++ni) {
        const int col = bcol + wc * 64 + ni * 16 + lr;
        int nn = col;
        const float* bp = bias0;
        if constexpr (MODE == 5) {
            const int sub = col >> 10;
            nn = col & 1023;
            bp = (sub == 0) ? bias0 : (sub == 1 ? bias1 : bias2);
        }
        const float bval = bp[nn];
#pragma unroll
        for (int mi = 0; mi < 4; ++mi) {
#pragma unroll
            for (int j = 0; j < 4; ++j) {
                const int row = brow + wr * 64 + mi * 16 + lg * 4 + j;
                float v = acc[mi][ni][j] + bval;
                if constexpr (MODE == 3) {
                    ((float*)out0)[(size_t)row * N + col] = v + res[(size_t)row * N + col];
                } else if constexpr (MODE == 5) {
                    const int sub = col >> 10;
                    bf16 h, lo2; split2(v, h, lo2);
                    if (sub < 2) {
                        bf16* dst = (bf16*)(sub == 0 ? out0 : out1);
                        dst[(size_t)row * DM + nn] = h;
                        dst[(size_t)row * DM + nn + loStride] = lo2;
                    } else {
                        const int bb = row >> 11, sI = row & (SEQ - 1);
                        const int hh = nn >> 6, d = nn & 63;
                        const size_t idx = (((size_t)((bb * NH + hh) * HD + d)) << 11) + sI;
                        ((bf16*)out2)[idx] = h;
                        ((bf16*)out2)[idx + loStride] = lo2;
                    }
                }
            }
        }
    }
}

// =======================================================================
// gemm_bt5a: gemm_bt MODE5 with the A-lo plane deleted (R11-proven
// deletion class). C = Ah * (Bh+Bl)^T; acc = Ah*Bh + Ah*Bl. 48KB LDS.
// Fused QKV epilogue verbatim: q(out0)/k(out1) split planes, v^T(out2).
// =======================================================================
__global__ __launch_bounds__(256) void gemm_bt5a(
    const bf16* __restrict__ Ah,
    const bf16* __restrict__ Bh, const bf16* __restrict__ Bl,
    const float* __restrict__ bias0, const float* __restrict__ bias1,
    const float* __restrict__ bias2,
    void* __restrict__ out0, void* __restrict__ out1, void* __restrict__ out2,
    size_t loStride, int M, int N, int K) {
    __shared__ alignas(16) bf16 Ash[128 * 64];
    __shared__ alignas(16) bf16 Bsh[128 * 64];
    __shared__ alignas(16) bf16 Bsl[128 * 64];
    const int t  = threadIdx.x;
    const int l  = t & 63;
    const int w  = t >> 6;
    const int wr = w >> 1, wc = w & 1;
    const int lg = l >> 4, lr = l & 15;
    // XCD-chunked remap (all grids have nwg % 8 == 0)
    const int nwg  = gridDim.x * gridDim.y;
    const int bidl = blockIdx.y * gridDim.x + blockIdx.x;
    const int swz  = (bidl & 7) * (nwg >> 3) + (bidl >> 3);
    const int brow = (swz / gridDim.x) * 128;
    const int bcol = (swz % gridDim.x) * 128;

    f32x4 acc[4][4] = {};

    const bf16* Abh = Ah + (size_t)brow * K;
    const bf16* Bbh = Bh + (size_t)bcol * K;
    const bf16* Bbl = Bl + (size_t)bcol * K;
    const int wb8 = (t & ~63) * 8;

    for (int kt = 0; kt < K; kt += 64) {
#pragma unroll
        for (int r = 0; r < 4; ++r) {
            const int e = (r * 256 + t) * 8;
            const int row = e >> 6, col = e & 63;
            const size_t go = (size_t)row * K + kt + col;
            gload16(Abh + go, &Ash[r * 2048 + wb8]);
            gload16(Bbh + go, &Bsh[r * 2048 + wb8]);
            gload16(Bbl + go, &Bsl[r * 2048 + wb8]);
        }
        __syncthreads();
#pragma unroll
        for (int ks = 0; ks < 2; ++ks) {
            bf16x8 afh[4], bfh[4], bfl[4];
#pragma unroll
            for (int mi = 0; mi < 4; ++mi) {
                const int off = (wr * 64 + mi * 16 + lr) * 64 + ks * 32 + lg * 8;
                afh[mi] = *(const bf16x8*)&Ash[off];
            }
#pragma unroll
            for (int ni = 0; ni < 4; ++ni) {
                const int off = (wc * 64 + ni * 16 + lr) * 64 + ks * 32 + lg * 8;
                bfh[ni] = *(const bf16x8*)&Bsh[off];
                bfl[ni] = *(const bf16x8*)&Bsl[off];
            }
#pragma unroll
            for (int mi = 0; mi < 4; ++mi)
#pragma unroll
                for (int ni = 0; ni < 4; ++ni) {
                    mfma16(acc[mi][ni], afh[mi], bfh[ni]);
                    mfma16(acc[mi][ni], afh[mi], bfl[ni]);
                }
        }
        __syncthreads();
    }

    // epilogue: C/D layout col=lane&15, row=(lane>>4)*4+j  [m89]
#pragma unroll
    for (int ni = 0; ni < 4; ++ni) {
        const int col = bcol + wc * 64 + ni * 16 + lr;
        const int sub = col >> 10;
        const int nn = col & 1023;
        const float* bp = (sub == 0) ? bias0 : (sub == 1 ? bias1 : bias2);
        const float bval = bp[nn];
#pragma unroll
        for (int mi = 0; mi < 4; ++mi) {
#pragma unroll
            for (int j = 0; j < 4; ++j) {
                const int row = brow + wr * 64 + mi * 16 + lg * 4 + j;
                float v = acc[mi][ni][j] + bval;
                bf16 h, lo2; split2(v, h, lo2);
                if (sub < 2) {
                    bf16* dst = (bf16*)(sub == 0 ? out0 : out1);
                    dst[(size_t)row * DM + nn] = h;
                    dst[(size_t)row * DM + nn + loStride] = lo2;
                } else {
                    const int bb = row >> 11, sI = row & (SEQ - 1);
                    const int hh = nn >> 6, d = nn & 63;
                    const size_t idx = (((size_t)((bb * NH + hh) * HD + d)) << 11) + sI;
                    ((bf16*)out2)[idx] = h;
                    ((bf16*)out2)[idx + loStride] = lo2;
                }
            }
        }
    }
}

// =======================================================================
// gemm_bt2 (R11-verbatim): C = Ah[M][K] * (Bh+Bl)[N][K]^T; 48KB LDS.
// MODE 3: fp32 out0 = acc + bias0[n] + res[m][n]
// MODE 4: bf16 out0 = gelu_tanh(acc + bias0[n])  (hi plane only)
// =======================================================================
template <int MODE>
__global__ __launch_bounds__(256) void gemm_bt2(
    const bf16* __restrict__ Ah,
    const bf16* __restrict__ Bh, const bf16* __restrict__ Bl,
    const float* __restrict__ bias0, const float* __restrict__ res,
    void* __restrict__ out0, int M, int N, int K) {
    __shared__ alignas(16) bf16 Ash[128 * 64];
    __shared__ alignas(16) bf16 Bsh[128 * 64];
    __shared__ alignas(16) bf16 Bsl[128 * 64];
    const int t  = threadIdx.x;
    const int l  = t & 63;
    const int w  = t >> 6;
    const int wr = w >> 1, wc = w & 1;
    const int lg = l >> 4, lr = l & 15;
    // XCD-chunked remap (all grids have nwg % 8 == 0)
    const int nwg  = gridDim.x * gridDim.y;
    const int bidl = blockIdx.y * gridDim.x + blockIdx.x;
    const int swz  = (bidl & 7) * (nwg >> 3) + (bidl >> 3);
    const int brow = (swz / gridDim.x) * 128;
    const int bcol = (swz % gridDim.x) * 128;

    f32x4 acc[4][4] = {};

    const bf16* Abh = Ah + (size_t)brow * K;
    const bf16* Bbh = Bh + (size_t)bcol * K;
    const bf16* Bbl = Bl + (size_t)bcol * K;
    const int wb8 = (t & ~63) * 8;

    for (int kt = 0; kt < K; kt += 64) {
#pragma unroll
        for (int r = 0; r < 4; ++r) {
            const int e = (r * 256 + t) * 8;
            const int row = e >> 6, col = e & 63;
            const size_t go = (size_t)row * K + kt + col;
            gload16(Abh + go, &Ash[r * 2048 + wb8]);
            gload16(Bbh + go, &Bsh[r * 2048 + wb8]);
            gload16(Bbl + go, &Bsl[r * 2048 + wb8]);
        }
        __syncthreads();
#pragma unroll
        for (int ks = 0; ks < 2; ++ks) {
            bf16x8 afh[4], bfh[4], bfl[4];
#pragma unroll
            for (int mi = 0; mi < 4; ++mi) {
                const int off = (wr * 64 + mi * 16 + lr) * 64 + ks * 32 + lg * 8;
                afh[mi] = *(const bf16x8*)&Ash[off];
            }
#pragma unroll
            for (int ni = 0; ni < 4; ++ni) {
                const int off = (wc * 64 + ni * 16 + lr) * 64 + ks * 32 + lg * 8;
                bfh[ni] = *(const bf16x8*)&Bsh[off];
                bfl[ni] = *(const bf16x8*)&Bsl[off];
            }
#pragma unroll
            for (int mi = 0; mi < 4; ++mi)
#pragma unroll
                for (int ni = 0; ni < 4; ++ni) {
                    mfma16(acc[mi][ni], afh[mi], bfh[ni]);
                    mfma16(acc[mi][ni], afh[mi], bfl[ni]);
                }
        }
        __syncthreads();
    }

    // epilogue: C/D layout col=lane&15, row=(lane>>4)*4+j  [m89]
#pragma unroll
    for (int ni = 0; ni < 4; ++ni) {
        const int col = bcol + wc * 64 + ni * 16 + lr;
        const float bval = bias0[col];
#pragma unroll
        for (int mi = 0; mi < 4; ++mi) {
#pragma unroll
            for (int j = 0; j < 4; ++j) {
                const int row = brow + wr * 64 + mi * 16 + lg * 4 + j;
                float v = acc[mi][ni][j] + bval;
                if constexpr (MODE == 3) {
                    ((float*)out0)[(size_t)row * N + col] = v + res[(size_t)row * N + col];
                } else if constexpr (MODE == 4) {
                    const float u = 0.7978845608028654f * (v + 0.044715f * v * v * v);
                    const float g = 0.5f * v * (1.0f + tanhf(u));
                    ((bf16*)out0)[(size_t)row * N + col] = (bf16)g;
                }
            }
        }
    }
}

// =======================================================================
// Causal flash attention, split-precision Q/K/P/V — R11-VERBATIM (frozen).
// R7 body + R9 mapping (complementary qt pairing + XCD-local bh).
// The P-LDS two-plane path is load-bearing: every variant that touched it
// (R3/R4/R5/R6/R8/R12) failed; do not modify.
// =======================================================================
__global__ __launch_bounds__(256) void attn_kernel(
    const bf16* __restrict__ qh, const bf16* __restrict__ ql,
    const bf16* __restrict__ kh, const bf16* __restrict__ kl,
    const bf16* __restrict__ vth, const bf16* __restrict__ vtl,
    bf16* __restrict__ oh, bf16* __restrict__ ol) {
    __shared__ alignas(16) bf16 Ksh[64 * 64], Ksl[64 * 64];
    __shared__ alignas(16) bf16 Vsh[64 * 64], Vsl[64 * 64];   // [hd][kv]
    __shared__ alignas(16) bf16 Psh[4][32 * 64], Psl[4][32 * 64];
    const int bid = blockIdx.x;                 // 0..511
    const int qtidx = (bid >> 3) & 15;
    const int qt = (bid & 256) ? (15 - qtidx) : qtidx;  // complementary pairing
    const int bh = (bid & 7) + 8 * (bid >> 7);  // head-group -> fixed XCD slot
    const int b = bh >> 4, h = bh & 15;
    const int t = threadIdx.x;
    const int w = t >> 6, l = t & 63;
    const int lg = l >> 4, lr = l & 15;
    const int qrow0 = qt * 128 + w * 32;
    const size_t tokbase = (size_t)b * SEQ;

    bf16x8 qfh[2][2], qfl[2][2];
#pragma unroll
    for (int mi = 0; mi < 2; ++mi)
#pragma unroll
        for (int ks = 0; ks < 2; ++ks) {
            const size_t off = (tokbase + qrow0 + mi * 16 + lr) * DM + h * HD + ks * 32 + lg * 8;
            qfh[mi][ks] = *(const bf16x8*)&qh[off];
            qfl[mi][ks] = *(const bf16x8*)&ql[off];
        }

    f32x4 oacc[2][4] = {};
    float mrow[2][4], lrow[2][4];
#pragma unroll
    for (int mi = 0; mi < 2; ++mi)
#pragma unroll
        for (int j = 0; j < 4; ++j) { mrow[mi][j] = -1e30f; lrow[mi][j] = 0.f; }

    const int wb8 = (t & ~63) * 8;
    const int nkv = 2 * (qt + 1);
    for (int kt = 0; kt < nkv; ++kt) {
#pragma unroll
        for (int r = 0; r < 2; ++r) {
            const int e = (r * 256 + t) * 8;
            const int rr = e >> 6, cc = e & 63;
            const size_t kg = (tokbase + kt * 64 + rr) * DM + h * HD + cc;
            const size_t vg = (((size_t)((b * NH + h) * HD + rr)) << 11) + kt * 64 + cc;
            gload16(&kh[kg], &Ksh[r * 2048 + wb8]);
            gload16(&kl[kg], &Ksl[r * 2048 + wb8]);
            gload16(&vth[vg], &Vsh[r * 2048 + wb8]);
            gload16(&vtl[vg], &Vsl[r * 2048 + wb8]);
        }
        __syncthreads();
        const bool active = (kt * 64 <= qrow0 + 31);
        if (active) {
            f32x4 sf[2][4] = {};
#pragma unroll
            for (int ks = 0; ks < 2; ++ks)
#pragma unroll
                for (int ni = 0; ni < 4; ++ni) {
                    const int off = (ni * 16 + lr) * 64 + ks * 32 + lg * 8;
                    const bf16x8 kfh = *(const bf16x8*)&Ksh[off];
                    const bf16x8 kfl = *(const bf16x8*)&Ksl[off];
#pragma unroll
                    for (int mi = 0; mi < 2; ++mi) {
                        mfma16(sf[mi][ni], qfh[mi][ks], kfh);
                        mfma16(sf[mi][ni], qfh[mi][ks], kfl);
                        mfma16(sf[mi][ni], qfl[mi][ks], kfh);
                    }
                }
#pragma unroll
            for (int mi = 0; mi < 2; ++mi)
#pragma unroll
                for (int ni = 0; ni < 4; ++ni)
#pragma unroll
                    for (int j = 0; j < 4; ++j) {
                        const float sv = sf[mi][ni][j] * 0.125f;
                        const int qg = qrow0 + mi * 16 + lg * 4 + j;
                        const int kg = kt * 64 + ni * 16 + lr;
                        sf[mi][ni][j] = (kg > qg) ? -1e30f : sv;
                    }
#pragma unroll
            for (int mi = 0; mi < 2; ++mi)
#pragma unroll
                for (int j = 0; j < 4; ++j) {
                    float pm = fmaxf(fmaxf(sf[mi][0][j], sf[mi][1][j]),
                                     fmaxf(sf[mi][2][j], sf[mi][3][j]));
#pragma unroll
                    for (int msk = 1; msk <= 8; msk <<= 1)
                        pm = fmaxf(pm, __shfl_xor(pm, msk));
                    const float mnew = fmaxf(mrow[mi][j], pm);
                    const float resc = __expf(mrow[mi][j] - mnew);
                    mrow[mi][j] = mnew;
                    float rsum = 0.f;
#pragma unroll
                    for (int ni = 0; ni < 4; ++ni) {
                        const float p = __expf(sf[mi][ni][j] - mnew);
                        sf[mi][ni][j] = p;
                        rsum += p;
                    }
#pragma unroll
                    for (int msk = 1; msk <= 8; msk <<= 1)
                        rsum += __shfl_xor(rsum, msk);
                    lrow[mi][j] = lrow[mi][j] * resc + rsum;
#pragma unroll
                    for (int di = 0; di < 4; ++di) oacc[mi][di][j] *= resc;
                }
#pragma unroll
            for (int mi = 0; mi < 2; ++mi)
#pragma unroll
                for (int ni = 0; ni < 4; ++ni)
#pragma unroll
                    for (int j = 0; j < 4; ++j) {
                        const float p = sf[mi][ni][j];
                        const int idx = (mi * 16 + lg * 4 + j) * 64 + ni * 16 + lr;
                        bf16 hh, lo2; split2(p, hh, lo2);
                        Psh[w][idx] = hh;
                        Psl[w][idx] = lo2;
                    }
#pragma unroll
            for (int ks = 0; ks < 2; ++ks) {
                bf16x8 pah[2], pal[2];
#pragma unroll
                for (int mi = 0; mi < 2; ++mi) {
                    const int off = (mi * 16 + lr) * 64 + ks * 32 + lg * 8;
                    pah[mi] = *(const bf16x8*)&Psh[w][off];
                    pal[mi] = *(const bf16x8*)&Psl[w][off];
                }
#pragma unroll
                for (int di = 0; di < 4; ++di) {
                    const int off = (di * 16 + lr) * 64 + ks * 32 + lg * 8;
                    const bf16x8 vfh = *(const bf16x8*)&Vsh[off];
                    const bf16x8 vfl = *(const bf16x8*)&Vsl[off];
#pragma unroll
                    for (int mi = 0; mi < 2; ++mi) {
                        mfma16(oacc[mi][di], pah[mi], vfh);
                        mfma16(oacc[mi][di], pah[mi], vfl);
                        mfma16(oacc[mi][di], pal[mi], vfh);
                    }
                }
            }
        }
        __syncthreads();
    }
#pragma unroll
    for (int mi = 0; mi < 2; ++mi)
#pragma unroll
        for (int j = 0; j < 4; ++j) {
            const float inv = 1.0f / lrow[mi][j];
            const int row = qrow0 + mi * 16 + lg * 4 + j;
#pragma unroll
            for (int di = 0; di < 4; ++di) {
                const float f = oacc[mi][di][j] * inv;
                bf16 hh, lo2; split2(f, hh, lo2);
                const size_t idx = (tokbase + row) * DM + h * HD + di * 16 + lr;
                oh[idx] = hh;
                ol[idx] = lo2;
            }
        }
}

// =======================================================================
extern "C" void kernel_launch(void* const* d_in, const int* in_sizes, int n_in,
                              void* d_out, int out_size, void* d_ws, size_t ws_size,
                              hipStream_t stream) {
    const float* x    = (const float*)d_in[0];
    const float* ln1s = (const float*)d_in[2];
    const float* ln1b = (const float*)d_in[3];
    const float* Wq   = (const float*)d_in[4];
    const float* bq   = (const float*)d_in[5];
    const float* Wk   = (const float*)d_in[6];
    const float* bk   = (const float*)d_in[7];
    const float* Wv   = (const float*)d_in[8];
    const float* bv   = (const float*)d_in[9];
    const float* Wo   = (const float*)d_in[10];
    const float* bo   = (const float*)d_in[11];
    const float* ln2s = (const float*)d_in[12];
    const float* ln2b = (const float*)d_in[13];
    const float* W1   = (const float*)d_in[14];
    const float* b1   = (const float*)d_in[15];
    const float* W2   = (const float*)d_in[16];
    const float* b2   = (const float*)d_in[17];
    float* out = (float*)d_out;

    const size_t M1 = (size_t)1024 * 1024;  // 1M elems
    bf16* ws = (bf16*)d_ws;
    // weights (split planes)
    bf16* Wqkv_h = ws;                 // 3M
    bf16* Wqkv_l = ws + 3 * M1;        // 3M
    bf16* Wo_h   = ws + 6 * M1;
    bf16* Wo_l   = ws + 7 * M1;
    bf16* W1_h   = ws + 8 * M1;        // 4M
    bf16* W1_l   = ws + 12 * M1;
    bf16* W2_h   = ws + 16 * M1;       // 4M
    bf16* W2_l   = ws + 20 * M1;
    // activations
    bf16*  xn_h  = ws + 24 * M1;       // 4M
    bf16*  xn_l  = ws + 28 * M1;
    float* x1    = (float*)(ws + 32 * M1);  // 4M fp32 (8M slots)
    bf16*  q_h   = ws + 40 * M1;
    bf16*  q_l   = ws + 44 * M1;
    bf16*  k_h   = ws + 48 * M1;
    bf16*  k_l   = ws + 52 * M1;
    bf16*  vt_h  = ws + 56 * M1;
    bf16*  vt_l  = ws + 60 * M1;
    bf16*  o_h   = ws + 64 * M1;
    bf16*  o_l   = ws + 68 * M1;       // ends 72M elems = 144MB
    // MLP hidden (hi only) overlays q..o region (dead after O-proj)
    bf16*  h_h   = ws + 40 * M1;       // 16M

    const dim3 blk(256);
    transpose_convert<<<dim3(32, 32), blk, 0, stream>>>(Wq, Wqkv_h,      Wqkv_l,      1024, 1024);
    transpose_convert<<<dim3(32, 32), blk, 0, stream>>>(Wk, Wqkv_h + M1, Wqkv_l + M1, 1024, 1024);
    transpose_convert<<<dim3(32, 32), blk, 0, stream>>>(Wv, Wqkv_h + 2*M1, Wqkv_l + 2*M1, 1024, 1024);
    transpose_convert<<<dim3(32, 32), blk, 0, stream>>>(Wo, Wo_h, Wo_l, 1024, 1024);
    transpose_convert<<<dim3(128, 32), blk, 0, stream>>>(W1, W1_h, W1_l, 1024, 4096);
    transpose_convert<<<dim3(32, 128), blk, 0, stream>>>(W2, W2_h, W2_l, 4096, 1024);

    layernorm_kernel<<<NTOK, blk, 0, stream>>>(x, ln1s, ln1b, xn_h, xn_l);

    // fused QKV: A hi-only x split Wqkv (R11-proven deletion class)
    gemm_bt5a<<<dim3(24, 32), blk, 0, stream>>>(xn_h, Wqkv_h, Wqkv_l,
        bq, bk, bv, q_h, k_h, vt_h, 4 * M1, NTOK, 3072, 1024);

    attn_kernel<<<512, blk, 0, stream>>>(q_h, q_l, k_h, k_l, vt_h, vt_l, o_h, o_l);

    gemm_bt<3><<<dim3(8, 32), blk, 0, stream>>>(o_h, o_l, Wo_h, Wo_l,
        bo, nullptr, nullptr, x, x1, nullptr, nullptr, 0, NTOK, 1024, 1024);

    layernorm_kernel<<<NTOK, blk, 0, stream>>>(x1, ln2s, ln2b, xn_h, xn_l);

    // MLP up + GELU (A hi-only x split W1 -> bf16 h, hi plane)
    gemm_bt2<4><<<dim3(32, 32), blk, 0, stream>>>(xn_h, W1_h, W1_l,
        b1, nullptr, h_h, NTOK, DFF, 1024);

    // MLP down + residual -> out (A hi-only x split W2)
    gemm_bt2<3><<<dim3(8, 32), blk, 0, stream>>>(h_h, W2_h, W2_l,
        b2, x1, out, NTOK, 1024, DFF);
}

// Round 14
// 430.232 us; speedup vs baseline: 1.4117x; 1.1850x over previous
//
#include <hip/hip_runtime.h>
#include <cmath>

#define DM   1024
#define DFF  4096
#define NH   16
#define HD   64
#define SEQ  2048
#define NB   2
#define NTOK (NB * SEQ)  // 4096

typedef __bf16 bf16;
typedef __bf16 bf16x8 __attribute__((ext_vector_type(8)));
typedef float  f32x4  __attribute__((ext_vector_type(4)));

// ---- MFMA via inline asm ----
__device__ __forceinline__ void mfma16(f32x4& acc, bf16x8 a, bf16x8 b) {
    asm("v_mfma_f32_16x16x32_bf16 %0, %1, %2, %0" : "+v"(acc) : "v"(a), "v"(b));
}
// ---- async global->LDS, 16B/lane; LDS base must be wave-uniform ----
__device__ __forceinline__ void gload16(const void* g, void* l) {
    __builtin_amdgcn_global_load_lds(
        (__attribute__((address_space(1))) void*)(void*)g,
        (__attribute__((address_space(3))) void*)l, 16, 0, 0);
}
// ---- fp32 -> (hi, lo) bf16 pair; hi+lo ~ 16-bit-mantissa accurate ----
__device__ __forceinline__ void split2(float v, bf16& h, bf16& l) {
    h = (bf16)v; l = (bf16)(v - (float)h);
}

// =======================================================================
// Weight transpose + fp32 -> split bf16:  W[K][N] -> Wth/Wtl [N][K]
// =======================================================================
__global__ __launch_bounds__(256) void transpose_convert(
    const float* __restrict__ W, bf16* __restrict__ Wth, bf16* __restrict__ Wtl,
    int K, int N) {
    __shared__ float tile[32][33];
    const int bn = blockIdx.x * 32;
    const int bk = blockIdx.y * 32;
    const int tx = threadIdx.x & 31;
    const int ty = (threadIdx.x >> 5) << 2;
#pragma unroll
    for (int i = 0; i < 4; ++i)
        tile[ty + i][tx] = W[(size_t)(bk + ty + i) * N + bn + tx];
    __syncthreads();
#pragma unroll
    for (int i = 0; i < 4; ++i) {
        const float v = tile[tx][ty + i];
        bf16 h, l; split2(v, h, l);
        Wth[(size_t)(bn + ty + i) * K + bk + tx] = h;
        Wtl[(size_t)(bn + ty + i) * K + bk + tx] = l;
    }
}

// =======================================================================
// LayerNorm, fp32 in -> split bf16 out
// =======================================================================
__global__ __launch_bounds__(256) void layernorm_kernel(
    const float* __restrict__ x, const float* __restrict__ scale,
    const float* __restrict__ bias, bf16* __restrict__ oh, bf16* __restrict__ ol) {
    const int row = blockIdx.x;
    const int t = threadIdx.x;
    const float4 v = ((const float4*)(x + (size_t)row * DM))[t];
    float s  = v.x + v.y + v.z + v.w;
    float ss = v.x * v.x + v.y * v.y + v.z * v.z + v.w * v.w;
#pragma unroll
    for (int m = 1; m < 64; m <<= 1) {
        s  += __shfl_xor(s, m);
        ss += __shfl_xor(ss, m);
    }
    __shared__ float red[2][4];
    const int w = t >> 6;
    if ((t & 63) == 0) { red[0][w] = s; red[1][w] = ss; }
    __syncthreads();
    s  = red[0][0] + red[0][1] + red[0][2] + red[0][3];
    ss = red[1][0] + red[1][1] + red[1][2] + red[1][3];
    const float mu = s * (1.0f / DM);
    const float rs = rsqrtf(ss * (1.0f / DM) - mu * mu + 1e-6f);
    const float4 sc = ((const float4*)scale)[t];
    const float4 bi = ((const float4*)bias)[t];
    const float y[4] = {(v.x - mu) * rs * sc.x + bi.x, (v.y - mu) * rs * sc.y + bi.y,
                        (v.z - mu) * rs * sc.z + bi.z, (v.w - mu) * rs * sc.w + bi.w};
#pragma unroll
    for (int i = 0; i < 4; ++i) {
        bf16 h, l; split2(y[i], h, l);
        oh[(size_t)row * DM + t * 4 + i] = h;
        ol[(size_t)row * DM + t * 4 + i] = l;
    }
}

// =======================================================================
// Split GEMM (R10-verbatim): C = (Ah+Al)[M][K] * (Bh+Bl)[N][K]^T
// acc = Ah*Bh + Ah*Bl + Al*Bh.  128x128 tile, BK=64, XCD-chunked remap.
// (Retained for potential fallback; currently unused by kernel_launch.)
// =======================================================================
template <int MODE>
__global__ __launch_bounds__(256) void gemm_bt(
    const bf16* __restrict__ Ah, const bf16* __restrict__ Al,
    const bf16* __restrict__ Bh, const bf16* __restrict__ Bl,
    const float* __restrict__ bias0, const float* __restrict__ bias1,
    const float* __restrict__ bias2, const float* __restrict__ res,
    void* __restrict__ out0, void* __restrict__ out1, void* __restrict__ out2,
    size_t loStride, int M, int N, int K) {
    __shared__ alignas(16) bf16 Ash[128 * 64];
    __shared__ alignas(16) bf16 Asl[128 * 64];
    __shared__ alignas(16) bf16 Bsh[128 * 64];
    __shared__ alignas(16) bf16 Bsl[128 * 64];
    const int t  = threadIdx.x;
    const int l  = t & 63;
    const int w  = t >> 6;
    const int wr = w >> 1, wc = w & 1;
    const int lg = l >> 4, lr = l & 15;
    const int nwg  = gridDim.x * gridDim.y;
    const int bidl = blockIdx.y * gridDim.x + blockIdx.x;
    const int swz  = (bidl & 7) * (nwg >> 3) + (bidl >> 3);
    const int brow = (swz / gridDim.x) * 128;
    const int bcol = (swz % gridDim.x) * 128;

    f32x4 acc[4][4] = {};

    const bf16* Abh = Ah + (size_t)brow * K;
    const bf16* Abl = Al + (size_t)brow * K;
    const bf16* Bbh = Bh + (size_t)bcol * K;
    const bf16* Bbl = Bl + (size_t)bcol * K;
    const int wb8 = (t & ~63) * 8;

    for (int kt = 0; kt < K; kt += 64) {
#pragma unroll
        for (int r = 0; r < 4; ++r) {
            const int e = (r * 256 + t) * 8;
            const int row = e >> 6, col = e & 63;
            const size_t go = (size_t)row * K + kt + col;
            gload16(Abh + go, &Ash[r * 2048 + wb8]);
            gload16(Abl + go, &Asl[r * 2048 + wb8]);
            gload16(Bbh + go, &Bsh[r * 2048 + wb8]);
            gload16(Bbl + go, &Bsl[r * 2048 + wb8]);
        }
        __syncthreads();
#pragma unroll
        for (int ks = 0; ks < 2; ++ks) {
            bf16x8 afh[4], afl[4], bfh[4], bfl[4];
#pragma unroll
            for (int mi = 0; mi < 4; ++mi) {
                const int off = (wr * 64 + mi * 16 + lr) * 64 + ks * 32 + lg * 8;
                afh[mi] = *(const bf16x8*)&Ash[off];
                afl[mi] = *(const bf16x8*)&Asl[off];
            }
#pragma unroll
            for (int ni = 0; ni < 4; ++ni) {
                const int off = (wc * 64 + ni * 16 + lr) * 64 + ks * 32 + lg * 8;
                bfh[ni] = *(const bf16x8*)&Bsh[off];
                bfl[ni] = *(const bf16x8*)&Bsl[off];
            }
#pragma unroll
            for (int mi = 0; mi < 4; ++mi)
#pragma unroll
                for (int ni = 0; ni < 4; ++ni) {
                    mfma16(acc[mi][ni], afh[mi], bfh[ni]);
                    mfma16(acc[mi][ni], afh[mi], bfl[ni]);
                    mfma16(acc[mi][ni], afl[mi], bfh[ni]);
                }
        }
        __syncthreads();
    }

#pragma unroll
    for (int ni = 0; ni < 4; ++ni) {
        const int col = bcol + wc * 64 + ni * 16 + lr;
        int nn = col;
        const float* bp = bias0;
        if constexpr (MODE == 5) {
            const int sub = col >> 10;
            nn = col & 1023;
            bp = (sub == 0) ? bias0 : (sub == 1 ? bias1 : bias2);
        }
        const float bval = bp[nn];
#pragma unroll
        for (int mi = 0; mi < 4; ++mi) {
#pragma unroll
            for (int j = 0; j < 4; ++j) {
                const int row = brow + wr * 64 + mi * 16 + lg * 4 + j;
                float v = acc[mi][ni][j] + bval;
                if constexpr (MODE == 3) {
                    ((float*)out0)[(size_t)row * N + col] = v + res[(size_t)row * N + col];
                } else if constexpr (MODE == 5) {
                    const int sub = col >> 10;
                    bf16 h, lo2; split2(v, h, lo2);
                    if (sub < 2) {
                        bf16* dst = (bf16*)(sub == 0 ? out0 : out1);
                        dst[(size_t)row * DM + nn] = h;
                        dst[(size_t)row * DM + nn + loStride] = lo2;
                    } else {
                        const int bb = row >> 11, sI = row & (SEQ - 1);
                        const int hh = nn >> 6, d = nn & 63;
                        const size_t idx = (((size_t)((bb * NH + hh) * HD + d)) << 11) + sI;
                        ((bf16*)out2)[idx] = h;
                        ((bf16*)out2)[idx + loStride] = lo2;
                    }
                }
            }
        }
    }
}

// =======================================================================
// gemm_bt5a (R13-verbatim): fused QKV, C = Ah * (Bh+Bl)^T. 48KB LDS.
// =======================================================================
__global__ __launch_bounds__(256) void gemm_bt5a(
    const bf16* __restrict__ Ah,
    const bf16* __restrict__ Bh, const bf16* __restrict__ Bl,
    const float* __restrict__ bias0, const float* __restrict__ bias1,
    const float* __restrict__ bias2,
    void* __restrict__ out0, void* __restrict__ out1, void* __restrict__ out2,
    size_t loStride, int M, int N, int K) {
    __shared__ alignas(16) bf16 Ash[128 * 64];
    __shared__ alignas(16) bf16 Bsh[128 * 64];
    __shared__ alignas(16) bf16 Bsl[128 * 64];
    const int t  = threadIdx.x;
    const int l  = t & 63;
    const int w  = t >> 6;
    const int wr = w >> 1, wc = w & 1;
    const int lg = l >> 4, lr = l & 15;
    const int nwg  = gridDim.x * gridDim.y;
    const int bidl = blockIdx.y * gridDim.x + blockIdx.x;
    const int swz  = (bidl & 7) * (nwg >> 3) + (bidl >> 3);
    const int brow = (swz / gridDim.x) * 128;
    const int bcol = (swz % gridDim.x) * 128;

    f32x4 acc[4][4] = {};

    const bf16* Abh = Ah + (size_t)brow * K;
    const bf16* Bbh = Bh + (size_t)bcol * K;
    const bf16* Bbl = Bl + (size_t)bcol * K;
    const int wb8 = (t & ~63) * 8;

    for (int kt = 0; kt < K; kt += 64) {
#pragma unroll
        for (int r = 0; r < 4; ++r) {
            const int e = (r * 256 + t) * 8;
            const int row = e >> 6, col = e & 63;
            const size_t go = (size_t)row * K + kt + col;
            gload16(Abh + go, &Ash[r * 2048 + wb8]);
            gload16(Bbh + go, &Bsh[r * 2048 + wb8]);
            gload16(Bbl + go, &Bsl[r * 2048 + wb8]);
        }
        __syncthreads();
#pragma unroll
        for (int ks = 0; ks < 2; ++ks) {
            bf16x8 afh[4], bfh[4], bfl[4];
#pragma unroll
            for (int mi = 0; mi < 4; ++mi) {
                const int off = (wr * 64 + mi * 16 + lr) * 64 + ks * 32 + lg * 8;
                afh[mi] = *(const bf16x8*)&Ash[off];
            }
#pragma unroll
            for (int ni = 0; ni < 4; ++ni) {
                const int off = (wc * 64 + ni * 16 + lr) * 64 + ks * 32 + lg * 8;
                bfh[ni] = *(const bf16x8*)&Bsh[off];
                bfl[ni] = *(const bf16x8*)&Bsl[off];
            }
#pragma unroll
            for (int mi = 0; mi < 4; ++mi)
#pragma unroll
                for (int ni = 0; ni < 4; ++ni) {
                    mfma16(acc[mi][ni], afh[mi], bfh[ni]);
                    mfma16(acc[mi][ni], afh[mi], bfl[ni]);
                }
        }
        __syncthreads();
    }

#pragma unroll
    for (int ni = 0; ni < 4; ++ni) {
        const int col = bcol + wc * 64 + ni * 16 + lr;
        const int sub = col >> 10;
        const int nn = col & 1023;
        const float* bp = (sub == 0) ? bias0 : (sub == 1 ? bias1 : bias2);
        const float bval = bp[nn];
#pragma unroll
        for (int mi = 0; mi < 4; ++mi) {
#pragma unroll
            for (int j = 0; j < 4; ++j) {
                const int row = brow + wr * 64 + mi * 16 + lg * 4 + j;
                float v = acc[mi][ni][j] + bval;
                bf16 h, lo2; split2(v, h, lo2);
                if (sub < 2) {
                    bf16* dst = (bf16*)(sub == 0 ? out0 : out1);
                    dst[(size_t)row * DM + nn] = h;
                    dst[(size_t)row * DM + nn + loStride] = lo2;
                } else {
                    const int bb = row >> 11, sI = row & (SEQ - 1);
                    const int hh = nn >> 6, d = nn & 63;
                    const size_t idx = (((size_t)((bb * NH + hh) * HD + d)) << 11) + sI;
                    ((bf16*)out2)[idx] = h;
                    ((bf16*)out2)[idx + loStride] = lo2;
                }
            }
        }
    }
}

// =======================================================================
// gemm_bt2 (R11-verbatim): C = Ah[M][K] * (Bh+Bl)[N][K]^T; 48KB LDS.
// MODE 3: fp32 out0 = acc + bias0[n] + res[m][n]
// MODE 4: bf16 out0 = gelu_tanh(acc + bias0[n])  (hi plane only)
// =======================================================================
template <int MODE>
__global__ __launch_bounds__(256) void gemm_bt2(
    const bf16* __restrict__ Ah,
    const bf16* __restrict__ Bh, const bf16* __restrict__ Bl,
    const float* __restrict__ bias0, const float* __restrict__ res,
    void* __restrict__ out0, int M, int N, int K) {
    __shared__ alignas(16) bf16 Ash[128 * 64];
    __shared__ alignas(16) bf16 Bsh[128 * 64];
    __shared__ alignas(16) bf16 Bsl[128 * 64];
    const int t  = threadIdx.x;
    const int l  = t & 63;
    const int w  = t >> 6;
    const int wr = w >> 1, wc = w & 1;
    const int lg = l >> 4, lr = l & 15;
    const int nwg  = gridDim.x * gridDim.y;
    const int bidl = blockIdx.y * gridDim.x + blockIdx.x;
    const int swz  = (bidl & 7) * (nwg >> 3) + (bidl >> 3);
    const int brow = (swz / gridDim.x) * 128;
    const int bcol = (swz % gridDim.x) * 128;

    f32x4 acc[4][4] = {};

    const bf16* Abh = Ah + (size_t)brow * K;
    const bf16* Bbh = Bh + (size_t)bcol * K;
    const bf16* Bbl = Bl + (size_t)bcol * K;
    const int wb8 = (t & ~63) * 8;

    for (int kt = 0; kt < K; kt += 64) {
#pragma unroll
        for (int r = 0; r < 4; ++r) {
            const int e = (r * 256 + t) * 8;
            const int row = e >> 6, col = e & 63;
            const size_t go = (size_t)row * K + kt + col;
            gload16(Abh + go, &Ash[r * 2048 + wb8]);
            gload16(Bbh + go, &Bsh[r * 2048 + wb8]);
            gload16(Bbl + go, &Bsl[r * 2048 + wb8]);
        }
        __syncthreads();
#pragma unroll
        for (int ks = 0; ks < 2; ++ks) {
            bf16x8 afh[4], bfh[4], bfl[4];
#pragma unroll
            for (int mi = 0; mi < 4; ++mi) {
                const int off = (wr * 64 + mi * 16 + lr) * 64 + ks * 32 + lg * 8;
                afh[mi] = *(const bf16x8*)&Ash[off];
            }
#pragma unroll
            for (int ni = 0; ni < 4; ++ni) {
                const int off = (wc * 64 + ni * 16 + lr) * 64 + ks * 32 + lg * 8;
                bfh[ni] = *(const bf16x8*)&Bsh[off];
                bfl[ni] = *(const bf16x8*)&Bsl[off];
            }
#pragma unroll
            for (int mi = 0; mi < 4; ++mi)
#pragma unroll
                for (int ni = 0; ni < 4; ++ni) {
                    mfma16(acc[mi][ni], afh[mi], bfh[ni]);
                    mfma16(acc[mi][ni], afh[mi], bfl[ni]);
                }
        }
        __syncthreads();
    }

#pragma unroll
    for (int ni = 0; ni < 4; ++ni) {
        const int col = bcol + wc * 64 + ni * 16 + lr;
        const float bval = bias0[col];
#pragma unroll
        for (int mi = 0; mi < 4; ++mi) {
#pragma unroll
            for (int j = 0; j < 4; ++j) {
                const int row = brow + wr * 64 + mi * 16 + lg * 4 + j;
                float v = acc[mi][ni][j] + bval;
                if constexpr (MODE == 3) {
                    ((float*)out0)[(size_t)row * N + col] = v + res[(size_t)row * N + col];
                } else if constexpr (MODE == 4) {
                    const float u = 0.7978845608028654f * (v + 0.044715f * v * v * v);
                    const float g = 0.5f * v * (1.0f + tanhf(u));
                    ((bf16*)out0)[(size_t)row * N + col] = (bf16)g;
                }
            }
        }
    }
}

// =======================================================================
// gemm_bt1: gemm_bt2 with the B-lo plane deleted (mirror of the proven
// A-lo deletion). C = Ah[M][K] * Bh[N][K]^T, 1 MFMA per fragment pair.
// 32KB LDS -> 5 blocks/CU. Used for the MLP GEMMs.
// MODE 3: fp32 out0 = acc + bias0[n] + res[m][n]
// MODE 4: bf16 out0 = gelu_tanh(acc + bias0[n])
// =======================================================================
template <int MODE>
__global__ __launch_bounds__(256) void gemm_bt1(
    const bf16* __restrict__ Ah,
    const bf16* __restrict__ Bh,
    const float* __restrict__ bias0, const float* __restrict__ res,
    void* __restrict__ out0, int M, int N, int K) {
    __shared__ alignas(16) bf16 Ash[128 * 64];
    __shared__ alignas(16) bf16 Bsh[128 * 64];
    const int t  = threadIdx.x;
    const int l  = t & 63;
    const int w  = t >> 6;
    const int wr = w >> 1, wc = w & 1;
    const int lg = l >> 4, lr = l & 15;
    const int nwg  = gridDim.x * gridDim.y;
    const int bidl = blockIdx.y * gridDim.x + blockIdx.x;
    const int swz  = (bidl & 7) * (nwg >> 3) + (bidl >> 3);
    const int brow = (swz / gridDim.x) * 128;
    const int bcol = (swz % gridDim.x) * 128;

    f32x4 acc[4][4] = {};

    const bf16* Abh = Ah + (size_t)brow * K;
    const bf16* Bbh = Bh + (size_t)bcol * K;
    const int wb8 = (t & ~63) * 8;

    for (int kt = 0; kt < K; kt += 64) {
#pragma unroll
        for (int r = 0; r < 4; ++r) {
            const int e = (r * 256 + t) * 8;
            const int row = e >> 6, col = e & 63;
            const size_t go = (size_t)row * K + kt + col;
            gload16(Abh + go, &Ash[r * 2048 + wb8]);
            gload16(Bbh + go, &Bsh[r * 2048 + wb8]);
        }
        __syncthreads();
#pragma unroll
        for (int ks = 0; ks < 2; ++ks) {
            bf16x8 afh[4], bfh[4];
#pragma unroll
            for (int mi = 0; mi < 4; ++mi) {
                const int off = (wr * 64 + mi * 16 + lr) * 64 + ks * 32 + lg * 8;
                afh[mi] = *(const bf16x8*)&Ash[off];
            }
#pragma unroll
            for (int ni = 0; ni < 4; ++ni) {
                const int off = (wc * 64 + ni * 16 + lr) * 64 + ks * 32 + lg * 8;
                bfh[ni] = *(const bf16x8*)&Bsh[off];
            }
#pragma unroll
            for (int mi = 0; mi < 4; ++mi)
#pragma unroll
                for (int ni = 0; ni < 4; ++ni) {
                    mfma16(acc[mi][ni], afh[mi], bfh[ni]);
                }
        }
        __syncthreads();
    }

#pragma unroll
    for (int ni = 0; ni < 4; ++ni) {
        const int col = bcol + wc * 64 + ni * 16 + lr;
        const float bval = bias0[col];
#pragma unroll
        for (int mi = 0; mi < 4; ++mi) {
#pragma unroll
            for (int j = 0; j < 4; ++j) {
                const int row = brow + wr * 64 + mi * 16 + lg * 4 + j;
                float v = acc[mi][ni][j] + bval;
                if constexpr (MODE == 3) {
                    ((float*)out0)[(size_t)row * N + col] = v + res[(size_t)row * N + col];
                } else if constexpr (MODE == 4) {
                    const float u = 0.7978845608028654f * (v + 0.044715f * v * v * v);
                    const float g = 0.5f * v * (1.0f + tanhf(u));
                    ((bf16*)out0)[(size_t)row * N + col] = (bf16)g;
                }
            }
        }
    }
}

// =======================================================================
// Causal flash attention, split-precision Q/K/P/V — R11-VERBATIM (frozen).
// R7 body + R9 mapping (complementary qt pairing + XCD-local bh).
// The P-LDS two-plane path is load-bearing: every variant that touched it
// (R3/R4/R5/R6/R8/R12) failed; do not modify.
// =======================================================================
__global__ __launch_bounds__(256) void attn_kernel(
    const bf16* __restrict__ qh, const bf16* __restrict__ ql,
    const bf16* __restrict__ kh, const bf16* __restrict__ kl,
    const bf16* __restrict__ vth, const bf16* __restrict__ vtl,
    bf16* __restrict__ oh, bf16* __restrict__ ol) {
    __shared__ alignas(16) bf16 Ksh[64 * 64], Ksl[64 * 64];
    __shared__ alignas(16) bf16 Vsh[64 * 64], Vsl[64 * 64];   // [hd][kv]
    __shared__ alignas(16) bf16 Psh[4][32 * 64], Psl[4][32 * 64];
    const int bid = blockIdx.x;                 // 0..511
    const int qtidx = (bid >> 3) & 15;
    const int qt = (bid & 256) ? (15 - qtidx) : qtidx;  // complementary pairing
    const int bh = (bid & 7) + 8 * (bid >> 7);  // head-group -> fixed XCD slot
    const int b = bh >> 4, h = bh & 15;
    const int t = threadIdx.x;
    const int w = t >> 6, l = t & 63;
    const int lg = l >> 4, lr = l & 15;
    const int qrow0 = qt * 128 + w * 32;
    const size_t tokbase = (size_t)b * SEQ;

    bf16x8 qfh[2][2], qfl[2][2];
#pragma unroll
    for (int mi = 0; mi < 2; ++mi)
#pragma unroll
        for (int ks = 0; ks < 2; ++ks) {
            const size_t off = (tokbase + qrow0 + mi * 16 + lr) * DM + h * HD + ks * 32 + lg * 8;
            qfh[mi][ks] = *(const bf16x8*)&qh[off];
            qfl[mi][ks] = *(const bf16x8*)&ql[off];
        }

    f32x4 oacc[2][4] = {};
    float mrow[2][4], lrow[2][4];
#pragma unroll
    for (int mi = 0; mi < 2; ++mi)
#pragma unroll
        for (int j = 0; j < 4; ++j) { mrow[mi][j] = -1e30f; lrow[mi][j] = 0.f; }

    const int wb8 = (t & ~63) * 8;
    const int nkv = 2 * (qt + 1);
    for (int kt = 0; kt < nkv; ++kt) {
#pragma unroll
        for (int r = 0; r < 2; ++r) {
            const int e = (r * 256 + t) * 8;
            const int rr = e >> 6, cc = e & 63;
            const size_t kg = (tokbase + kt * 64 + rr) * DM + h * HD + cc;
            const size_t vg = (((size_t)((b * NH + h) * HD + rr)) << 11) + kt * 64 + cc;
            gload16(&kh[kg], &Ksh[r * 2048 + wb8]);
            gload16(&kl[kg], &Ksl[r * 2048 + wb8]);
            gload16(&vth[vg], &Vsh[r * 2048 + wb8]);
            gload16(&vtl[vg], &Vsl[r * 2048 + wb8]);
        }
        __syncthreads();
        const bool active = (kt * 64 <= qrow0 + 31);
        if (active) {
            f32x4 sf[2][4] = {};
#pragma unroll
            for (int ks = 0; ks < 2; ++ks)
#pragma unroll
                for (int ni = 0; ni < 4; ++ni) {
                    const int off = (ni * 16 + lr) * 64 + ks * 32 + lg * 8;
                    const bf16x8 kfh = *(const bf16x8*)&Ksh[off];
                    const bf16x8 kfl = *(const bf16x8*)&Ksl[off];
#pragma unroll
                    for (int mi = 0; mi < 2; ++mi) {
                        mfma16(sf[mi][ni], qfh[mi][ks], kfh);
                        mfma16(sf[mi][ni], qfh[mi][ks], kfl);
                        mfma16(sf[mi][ni], qfl[mi][ks], kfh);
                    }
                }
#pragma unroll
            for (int mi = 0; mi < 2; ++mi)
#pragma unroll
                for (int ni = 0; ni < 4; ++ni)
#pragma unroll
                    for (int j = 0; j < 4; ++j) {
                        const float sv = sf[mi][ni][j] * 0.125f;
                        const int qg = qrow0 + mi * 16 + lg * 4 + j;
                        const int kg = kt * 64 + ni * 16 + lr;
                        sf[mi][ni][j] = (kg > qg) ? -1e30f : sv;
                    }
#pragma unroll
            for (int mi = 0; mi < 2; ++mi)
#pragma unroll
                for (int j = 0; j < 4; ++j) {
                    float pm = fmaxf(fmaxf(sf[mi][0][j], sf[mi][1][j]),
                                     fmaxf(sf[mi][2][j], sf[mi][3][j]));
#pragma unroll
                    for (int msk = 1; msk <= 8; msk <<= 1)
                        pm = fmaxf(pm, __shfl_xor(pm, msk));
                    const float mnew = fmaxf(mrow[mi][j], pm);
                    const float resc = __expf(mrow[mi][j] - mnew);
                    mrow[mi][j] = mnew;
                    float rsum = 0.f;
#pragma unroll
                    for (int ni = 0; ni < 4; ++ni) {
                        const float p = __expf(sf[mi][ni][j] - mnew);
                        sf[mi][ni][j] = p;
                        rsum += p;
                    }
#pragma unroll
                    for (int msk = 1; msk <= 8; msk <<= 1)
                        rsum += __shfl_xor(rsum, msk);
                    lrow[mi][j] = lrow[mi][j] * resc + rsum;
#pragma unroll
                    for (int di = 0; di < 4; ++di) oacc[mi][di][j] *= resc;
                }
#pragma unroll
            for (int mi = 0; mi < 2; ++mi)
#pragma unroll
                for (int ni = 0; ni < 4; ++ni)
#pragma unroll
                    for (int j = 0; j < 4; ++j) {
                        const float p = sf[mi][ni][j];
                        const int idx = (mi * 16 + lg * 4 + j) * 64 + ni * 16 + lr;
                        bf16 hh, lo2; split2(p, hh, lo2);
                        Psh[w][idx] = hh;
                        Psl[w][idx] = lo2;
                    }
#pragma unroll
            for (int ks = 0; ks < 2; ++ks) {
                bf16x8 pah[2], pal[2];
#pragma unroll
                for (int mi = 0; mi < 2; ++mi) {
                    const int off = (mi * 16 + lr) * 64 + ks * 32 + lg * 8;
                    pah[mi] = *(const bf16x8*)&Psh[w][off];
                    pal[mi] = *(const bf16x8*)&Psl[w][off];
                }
#pragma unroll
                for (int di = 0; di < 4; ++di) {
                    const int off = (di * 16 + lr) * 64 + ks * 32 + lg * 8;
                    const bf16x8 vfh = *(const bf16x8*)&Vsh[off];
                    const bf16x8 vfl = *(const bf16x8*)&Vsl[off];
#pragma unroll
                    for (int mi = 0; mi < 2; ++mi) {
                        mfma16(oacc[mi][di], pah[mi], vfh);
                        mfma16(oacc[mi][di], pah[mi], vfl);
                        mfma16(oacc[mi][di], pal[mi], vfh);
                    }
                }
            }
        }
        __syncthreads();
    }
#pragma unroll
    for (int mi = 0; mi < 2; ++mi)
#pragma unroll
        for (int j = 0; j < 4; ++j) {
            const float inv = 1.0f / lrow[mi][j];
            const int row = qrow0 + mi * 16 + lg * 4 + j;
#pragma unroll
            for (int di = 0; di < 4; ++di) {
                const float f = oacc[mi][di][j] * inv;
                bf16 hh, lo2; split2(f, hh, lo2);
                const size_t idx = (tokbase + row) * DM + h * HD + di * 16 + lr;
                oh[idx] = hh;
                ol[idx] = lo2;
            }
        }
}

// =======================================================================
extern "C" void kernel_launch(void* const* d_in, const int* in_sizes, int n_in,
                              void* d_out, int out_size, void* d_ws, size_t ws_size,
                              hipStream_t stream) {
    const float* x    = (const float*)d_in[0];
    const float* ln1s = (const float*)d_in[2];
    const float* ln1b = (const float*)d_in[3];
    const float* Wq   = (const float*)d_in[4];
    const float* bq   = (const float*)d_in[5];
    const float* Wk   = (const float*)d_in[6];
    const float* bk   = (const float*)d_in[7];
    const float* Wv   = (const float*)d_in[8];
    const float* bv   = (const float*)d_in[9];
    const float* Wo   = (const float*)d_in[10];
    const float* bo   = (const float*)d_in[11];
    const float* ln2s = (const float*)d_in[12];
    const float* ln2b = (const float*)d_in[13];
    const float* W1   = (const float*)d_in[14];
    const float* b1   = (const float*)d_in[15];
    const float* W2   = (const float*)d_in[16];
    const float* b2   = (const float*)d_in[17];
    float* out = (float*)d_out;

    const size_t M1 = (size_t)1024 * 1024;  // 1M elems
    bf16* ws = (bf16*)d_ws;
    // weights (split planes)
    bf16* Wqkv_h = ws;                 // 3M
    bf16* Wqkv_l = ws + 3 * M1;        // 3M
    bf16* Wo_h   = ws + 6 * M1;
    bf16* Wo_l   = ws + 7 * M1;
    bf16* W1_h   = ws + 8 * M1;        // 4M
    bf16* W1_l   = ws + 12 * M1;
    bf16* W2_h   = ws + 16 * M1;       // 4M
    bf16* W2_l   = ws + 20 * M1;
    // activations
    bf16*  xn_h  = ws + 24 * M1;       // 4M
    bf16*  xn_l  = ws + 28 * M1;
    float* x1    = (float*)(ws + 32 * M1);  // 4M fp32 (8M slots)
    bf16*  q_h   = ws + 40 * M1;
    bf16*  q_l   = ws + 44 * M1;
    bf16*  k_h   = ws + 48 * M1;
    bf16*  k_l   = ws + 52 * M1;
    bf16*  vt_h  = ws + 56 * M1;
    bf16*  vt_l  = ws + 60 * M1;
    bf16*  o_h   = ws + 64 * M1;
    bf16*  o_l   = ws + 68 * M1;       // ends 72M elems = 144MB
    // MLP hidden (hi only) overlays q..o region (dead after O-proj)
    bf16*  h_h   = ws + 40 * M1;       // 16M

    const dim3 blk(256);
    transpose_convert<<<dim3(32, 32), blk, 0, stream>>>(Wq, Wqkv_h,      Wqkv_l,      1024, 1024);
    transpose_convert<<<dim3(32, 32), blk, 0, stream>>>(Wk, Wqkv_h + M1, Wqkv_l + M1, 1024, 1024);
    transpose_convert<<<dim3(32, 32), blk, 0, stream>>>(Wv, Wqkv_h + 2*M1, Wqkv_l + 2*M1, 1024, 1024);
    transpose_convert<<<dim3(32, 32), blk, 0, stream>>>(Wo, Wo_h, Wo_l, 1024, 1024);
    transpose_convert<<<dim3(128, 32), blk, 0, stream>>>(W1, W1_h, W1_l, 1024, 4096);
    transpose_convert<<<dim3(32, 128), blk, 0, stream>>>(W2, W2_h, W2_l, 4096, 1024);

    layernorm_kernel<<<NTOK, blk, 0, stream>>>(x, ln1s, ln1b, xn_h, xn_l);

    // fused QKV: A hi-only x split Wqkv (R13-proven)
    gemm_bt5a<<<dim3(24, 32), blk, 0, stream>>>(xn_h, Wqkv_h, Wqkv_l,
        bq, bk, bv, q_h, k_h, vt_h, 4 * M1, NTOK, 3072, 1024);

    attn_kernel<<<512, blk, 0, stream>>>(q_h, q_l, k_h, k_l, vt_h, vt_l, o_h, o_l);

    // O projection + residual: A hi-only (drop o_l) x split Wo — proven kernel
    gemm_bt2<3><<<dim3(8, 32), blk, 0, stream>>>(o_h, Wo_h, Wo_l,
        bo, x, x1, NTOK, 1024, 1024);

    layernorm_kernel<<<NTOK, blk, 0, stream>>>(x1, ln2s, ln2b, xn_h, xn_l);

    // MLP up + GELU: plain bf16 x plain bf16 (B-lo deletion, 32KB LDS)
    gemm_bt1<4><<<dim3(32, 32), blk, 0, stream>>>(xn_h, W1_h,
        b1, nullptr, h_h, NTOK, DFF, 1024);

    // MLP down + residual -> out: plain bf16 x plain bf16
    gemm_bt1<3><<<dim3(8, 32), blk, 0, stream>>>(h_h, W2_h,
        b2, x1, out, NTOK, 1024, DFF);
}

// Round 15
// 401.493 us; speedup vs baseline: 1.5128x; 1.0716x over previous
//
#include <hip/hip_runtime.h>
#include <cmath>

#define DM   1024
#define DFF  4096
#define NH   16
#define HD   64
#define SEQ  2048
#define NB   2
#define NTOK (NB * SEQ)  // 4096

typedef __bf16 bf16;
typedef __bf16 bf16x8 __attribute__((ext_vector_type(8)));
typedef float  f32x4  __attribute__((ext_vector_type(4)));

// ---- MFMA via inline asm ----
__device__ __forceinline__ void mfma16(f32x4& acc, bf16x8 a, bf16x8 b) {
    asm("v_mfma_f32_16x16x32_bf16 %0, %1, %2, %0" : "+v"(acc) : "v"(a), "v"(b));
}
// ---- async global->LDS, 16B/lane; LDS base must be wave-uniform ----
__device__ __forceinline__ void gload16(const void* g, void* l) {
    __builtin_amdgcn_global_load_lds(
        (__attribute__((address_space(1))) void*)(void*)g,
        (__attribute__((address_space(3))) void*)l, 16, 0, 0);
}
// ---- fp32 -> (hi, lo) bf16 pair; hi+lo ~ 16-bit-mantissa accurate ----
__device__ __forceinline__ void split2(float v, bf16& h, bf16& l) {
    h = (bf16)v; l = (bf16)(v - (float)h);
}

// =======================================================================
// Weight transpose + fp32 -> split bf16:  W[K][N] -> Wth/Wtl [N][K]
// =======================================================================
__global__ __launch_bounds__(256) void transpose_convert(
    const float* __restrict__ W, bf16* __restrict__ Wth, bf16* __restrict__ Wtl,
    int K, int N) {
    __shared__ float tile[32][33];
    const int bn = blockIdx.x * 32;
    const int bk = blockIdx.y * 32;
    const int tx = threadIdx.x & 31;
    const int ty = (threadIdx.x >> 5) << 2;
#pragma unroll
    for (int i = 0; i < 4; ++i)
        tile[ty + i][tx] = W[(size_t)(bk + ty + i) * N + bn + tx];
    __syncthreads();
#pragma unroll
    for (int i = 0; i < 4; ++i) {
        const float v = tile[tx][ty + i];
        bf16 h, l; split2(v, h, l);
        Wth[(size_t)(bn + ty + i) * K + bk + tx] = h;
        Wtl[(size_t)(bn + ty + i) * K + bk + tx] = l;
    }
}

// =======================================================================
// transpose_convert_h: lo-plane store deleted (hi only).
// =======================================================================
__global__ __launch_bounds__(256) void transpose_convert_h(
    const float* __restrict__ W, bf16* __restrict__ Wth, int K, int N) {
    __shared__ float tile[32][33];
    const int bn = blockIdx.x * 32;
    const int bk = blockIdx.y * 32;
    const int tx = threadIdx.x & 31;
    const int ty = (threadIdx.x >> 5) << 2;
#pragma unroll
    for (int i = 0; i < 4; ++i)
        tile[ty + i][tx] = W[(size_t)(bk + ty + i) * N + bn + tx];
    __syncthreads();
#pragma unroll
    for (int i = 0; i < 4; ++i)
        Wth[(size_t)(bn + ty + i) * K + bk + tx] = (bf16)tile[tx][ty + i];
}

// =======================================================================
// LayerNorm, fp32 in -> split bf16 out (retained; unused)
// =======================================================================
__global__ __launch_bounds__(256) void layernorm_kernel(
    const float* __restrict__ x, const float* __restrict__ scale,
    const float* __restrict__ bias, bf16* __restrict__ oh, bf16* __restrict__ ol) {
    const int row = blockIdx.x;
    const int t = threadIdx.x;
    const float4 v = ((const float4*)(x + (size_t)row * DM))[t];
    float s  = v.x + v.y + v.z + v.w;
    float ss = v.x * v.x + v.y * v.y + v.z * v.z + v.w * v.w;
#pragma unroll
    for (int m = 1; m < 64; m <<= 1) {
        s  += __shfl_xor(s, m);
        ss += __shfl_xor(ss, m);
    }
    __shared__ float red[2][4];
    const int w = t >> 6;
    if ((t & 63) == 0) { red[0][w] = s; red[1][w] = ss; }
    __syncthreads();
    s  = red[0][0] + red[0][1] + red[0][2] + red[0][3];
    ss = red[1][0] + red[1][1] + red[1][2] + red[1][3];
    const float mu = s * (1.0f / DM);
    const float rs = rsqrtf(ss * (1.0f / DM) - mu * mu + 1e-6f);
    const float4 sc = ((const float4*)scale)[t];
    const float4 bi = ((const float4*)bias)[t];
    const float y[4] = {(v.x - mu) * rs * sc.x + bi.x, (v.y - mu) * rs * sc.y + bi.y,
                        (v.z - mu) * rs * sc.z + bi.z, (v.w - mu) * rs * sc.w + bi.w};
#pragma unroll
    for (int i = 0; i < 4; ++i) {
        bf16 h, l; split2(y[i], h, l);
        oh[(size_t)row * DM + t * 4 + i] = h;
        ol[(size_t)row * DM + t * 4 + i] = l;
    }
}

// =======================================================================
// layernorm_h: lo-plane store deleted (hi only).
// =======================================================================
__global__ __launch_bounds__(256) void layernorm_h(
    const float* __restrict__ x, const float* __restrict__ scale,
    const float* __restrict__ bias, bf16* __restrict__ oh) {
    const int row = blockIdx.x;
    const int t = threadIdx.x;
    const float4 v = ((const float4*)(x + (size_t)row * DM))[t];
    float s  = v.x + v.y + v.z + v.w;
    float ss = v.x * v.x + v.y * v.y + v.z * v.z + v.w * v.w;
#pragma unroll
    for (int m = 1; m < 64; m <<= 1) {
        s  += __shfl_xor(s, m);
        ss += __shfl_xor(ss, m);
    }
    __shared__ float red[2][4];
    const int w = t >> 6;
    if ((t & 63) == 0) { red[0][w] = s; red[1][w] = ss; }
    __syncthreads();
    s  = red[0][0] + red[0][1] + red[0][2] + red[0][3];
    ss = red[1][0] + red[1][1] + red[1][2] + red[1][3];
    const float mu = s * (1.0f / DM);
    const float rs = rsqrtf(ss * (1.0f / DM) - mu * mu + 1e-6f);
    const float4 sc = ((const float4*)scale)[t];
    const float4 bi = ((const float4*)bias)[t];
    const float y[4] = {(v.x - mu) * rs * sc.x + bi.x, (v.y - mu) * rs * sc.y + bi.y,
                        (v.z - mu) * rs * sc.z + bi.z, (v.w - mu) * rs * sc.w + bi.w};
    bf16 o0, o1, o2, o3;
    o0 = (bf16)y[0]; o1 = (bf16)y[1]; o2 = (bf16)y[2]; o3 = (bf16)y[3];
    bf16* dst = oh + (size_t)row * DM + t * 4;
    dst[0] = o0; dst[1] = o1; dst[2] = o2; dst[3] = o3;
}

// =======================================================================
// gemm_bt5a (R13-verbatim, retained; unused): fused QKV, C = Ah*(Bh+Bl)^T.
// =======================================================================
__global__ __launch_bounds__(256) void gemm_bt5a(
    const bf16* __restrict__ Ah,
    const bf16* __restrict__ Bh, const bf16* __restrict__ Bl,
    const float* __restrict__ bias0, const float* __restrict__ bias1,
    const float* __restrict__ bias2,
    void* __restrict__ out0, void* __restrict__ out1, void* __restrict__ out2,
    size_t loStride, int M, int N, int K) {
    __shared__ alignas(16) bf16 Ash[128 * 64];
    __shared__ alignas(16) bf16 Bsh[128 * 64];
    __shared__ alignas(16) bf16 Bsl[128 * 64];
    const int t  = threadIdx.x;
    const int l  = t & 63;
    const int w  = t >> 6;
    const int wr = w >> 1, wc = w & 1;
    const int lg = l >> 4, lr = l & 15;
    const int nwg  = gridDim.x * gridDim.y;
    const int bidl = blockIdx.y * gridDim.x + blockIdx.x;
    const int swz  = (bidl & 7) * (nwg >> 3) + (bidl >> 3);
    const int brow = (swz / gridDim.x) * 128;
    const int bcol = (swz % gridDim.x) * 128;

    f32x4 acc[4][4] = {};
    const bf16* Abh = Ah + (size_t)brow * K;
    const bf16* Bbh = Bh + (size_t)bcol * K;
    const bf16* Bbl = Bl + (size_t)bcol * K;
    const int wb8 = (t & ~63) * 8;

    for (int kt = 0; kt < K; kt += 64) {
#pragma unroll
        for (int r = 0; r < 4; ++r) {
            const int e = (r * 256 + t) * 8;
            const int row = e >> 6, col = e & 63;
            const size_t go = (size_t)row * K + kt + col;
            gload16(Abh + go, &Ash[r * 2048 + wb8]);
            gload16(Bbh + go, &Bsh[r * 2048 + wb8]);
            gload16(Bbl + go, &Bsl[r * 2048 + wb8]);
        }
        __syncthreads();
#pragma unroll
        for (int ks = 0; ks < 2; ++ks) {
            bf16x8 afh[4], bfh[4], bfl[4];
#pragma unroll
            for (int mi = 0; mi < 4; ++mi) {
                const int off = (wr * 64 + mi * 16 + lr) * 64 + ks * 32 + lg * 8;
                afh[mi] = *(const bf16x8*)&Ash[off];
            }
#pragma unroll
            for (int ni = 0; ni < 4; ++ni) {
                const int off = (wc * 64 + ni * 16 + lr) * 64 + ks * 32 + lg * 8;
                bfh[ni] = *(const bf16x8*)&Bsh[off];
                bfl[ni] = *(const bf16x8*)&Bsl[off];
            }
#pragma unroll
            for (int mi = 0; mi < 4; ++mi)
#pragma unroll
                for (int ni = 0; ni < 4; ++ni) {
                    mfma16(acc[mi][ni], afh[mi], bfh[ni]);
                    mfma16(acc[mi][ni], afh[mi], bfl[ni]);
                }
        }
        __syncthreads();
    }

#pragma unroll
    for (int ni = 0; ni < 4; ++ni) {
        const int col = bcol + wc * 64 + ni * 16 + lr;
        const int sub = col >> 10;
        const int nn = col & 1023;
        const float* bp = (sub == 0) ? bias0 : (sub == 1 ? bias1 : bias2);
        const float bval = bp[nn];
#pragma unroll
        for (int mi = 0; mi < 4; ++mi) {
#pragma unroll
            for (int j = 0; j < 4; ++j) {
                const int row = brow + wr * 64 + mi * 16 + lg * 4 + j;
                float v = acc[mi][ni][j] + bval;
                bf16 h, lo2; split2(v, h, lo2);
                if (sub < 2) {
                    bf16* dst = (bf16*)(sub == 0 ? out0 : out1);
                    dst[(size_t)row * DM + nn] = h;
                    dst[(size_t)row * DM + nn + loStride] = lo2;
                } else {
                    const int bb = row >> 11, sI = row & (SEQ - 1);
                    const int hh = nn >> 6, d = nn & 63;
                    const size_t idx = (((size_t)((bb * NH + hh) * HD + d)) << 11) + sI;
                    ((bf16*)out2)[idx] = h;
                    ((bf16*)out2)[idx + loStride] = lo2;
                }
            }
        }
    }
}

// =======================================================================
// gemm_bt5b: gemm_bt5a with the B-lo plane deleted (thrice-proven deletion
// class). C = Ah * Bh^T, 1 MFMA per fragment pair, 32KB LDS.
// Fused QKV epilogue verbatim: q/k split planes, v^T split planes.
// =======================================================================
__global__ __launch_bounds__(256) void gemm_bt5b(
    const bf16* __restrict__ Ah,
    const bf16* __restrict__ Bh,
    const float* __restrict__ bias0, const float* __restrict__ bias1,
    const float* __restrict__ bias2,
    void* __restrict__ out0, void* __restrict__ out1, void* __restrict__ out2,
    size_t loStride, int M, int N, int K) {
    __shared__ alignas(16) bf16 Ash[128 * 64];
    __shared__ alignas(16) bf16 Bsh[128 * 64];
    const int t  = threadIdx.x;
    const int l  = t & 63;
    const int w  = t >> 6;
    const int wr = w >> 1, wc = w & 1;
    const int lg = l >> 4, lr = l & 15;
    const int nwg  = gridDim.x * gridDim.y;
    const int bidl = blockIdx.y * gridDim.x + blockIdx.x;
    const int swz  = (bidl & 7) * (nwg >> 3) + (bidl >> 3);
    const int brow = (swz / gridDim.x) * 128;
    const int bcol = (swz % gridDim.x) * 128;

    f32x4 acc[4][4] = {};
    const bf16* Abh = Ah + (size_t)brow * K;
    const bf16* Bbh = Bh + (size_t)bcol * K;
    const int wb8 = (t & ~63) * 8;

    for (int kt = 0; kt < K; kt += 64) {
#pragma unroll
        for (int r = 0; r < 4; ++r) {
            const int e = (r * 256 + t) * 8;
            const int row = e >> 6, col = e & 63;
            const size_t go = (size_t)row * K + kt + col;
            gload16(Abh + go, &Ash[r * 2048 + wb8]);
            gload16(Bbh + go, &Bsh[r * 2048 + wb8]);
        }
        __syncthreads();
#pragma unroll
        for (int ks = 0; ks < 2; ++ks) {
            bf16x8 afh[4], bfh[4];
#pragma unroll
            for (int mi = 0; mi < 4; ++mi) {
                const int off = (wr * 64 + mi * 16 + lr) * 64 + ks * 32 + lg * 8;
                afh[mi] = *(const bf16x8*)&Ash[off];
            }
#pragma unroll
            for (int ni = 0; ni < 4; ++ni) {
                const int off = (wc * 64 + ni * 16 + lr) * 64 + ks * 32 + lg * 8;
                bfh[ni] = *(const bf16x8*)&Bsh[off];
            }
#pragma unroll
            for (int mi = 0; mi < 4; ++mi)
#pragma unroll
                for (int ni = 0; ni < 4; ++ni) {
                    mfma16(acc[mi][ni], afh[mi], bfh[ni]);
                }
        }
        __syncthreads();
    }

#pragma unroll
    for (int ni = 0; ni < 4; ++ni) {
        const int col = bcol + wc * 64 + ni * 16 + lr;
        const int sub = col >> 10;
        const int nn = col & 1023;
        const float* bp = (sub == 0) ? bias0 : (sub == 1 ? bias1 : bias2);
        const float bval = bp[nn];
#pragma unroll
        for (int mi = 0; mi < 4; ++mi) {
#pragma unroll
            for (int j = 0; j < 4; ++j) {
                const int row = brow + wr * 64 + mi * 16 + lg * 4 + j;
                float v = acc[mi][ni][j] + bval;
                bf16 h, lo2; split2(v, h, lo2);
                if (sub < 2) {
                    bf16* dst = (bf16*)(sub == 0 ? out0 : out1);
                    dst[(size_t)row * DM + nn] = h;
                    dst[(size_t)row * DM + nn + loStride] = lo2;
                } else {
                    const int bb = row >> 11, sI = row & (SEQ - 1);
                    const int hh = nn >> 6, d = nn & 63;
                    const size_t idx = (((size_t)((bb * NH + hh) * HD + d)) << 11) + sI;
                    ((bf16*)out2)[idx] = h;
                    ((bf16*)out2)[idx + loStride] = lo2;
                }
            }
        }
    }
}

// =======================================================================
// gemm_bt2 (R11-verbatim): C = Ah[M][K] * (Bh+Bl)[N][K]^T; 48KB LDS.
// MODE 3: fp32 out0 = acc + bias0[n] + res[m][n]
// MODE 4: bf16 out0 = gelu_tanh(acc + bias0[n])  (hi plane only)
// =======================================================================
template <int MODE>
__global__ __launch_bounds__(256) void gemm_bt2(
    const bf16* __restrict__ Ah,
    const bf16* __restrict__ Bh, const bf16* __restrict__ Bl,
    const float* __restrict__ bias0, const float* __restrict__ res,
    void* __restrict__ out0, int M, int N, int K) {
    __shared__ alignas(16) bf16 Ash[128 * 64];
    __shared__ alignas(16) bf16 Bsh[128 * 64];
    __shared__ alignas(16) bf16 Bsl[128 * 64];
    const int t  = threadIdx.x;
    const int l  = t & 63;
    const int w  = t >> 6;
    const int wr = w >> 1, wc = w & 1;
    const int lg = l >> 4, lr = l & 15;
    const int nwg  = gridDim.x * gridDim.y;
    const int bidl = blockIdx.y * gridDim.x + blockIdx.x;
    const int swz  = (bidl & 7) * (nwg >> 3) + (bidl >> 3);
    const int brow = (swz / gridDim.x) * 128;
    const int bcol = (swz % gridDim.x) * 128;

    f32x4 acc[4][4] = {};
    const bf16* Abh = Ah + (size_t)brow * K;
    const bf16* Bbh = Bh + (size_t)bcol * K;
    const bf16* Bbl = Bl + (size_t)bcol * K;
    const int wb8 = (t & ~63) * 8;

    for (int kt = 0; kt < K; kt += 64) {
#pragma unroll
        for (int r = 0; r < 4; ++r) {
            const int e = (r * 256 + t) * 8;
            const int row = e >> 6, col = e & 63;
            const size_t go = (size_t)row * K + kt + col;
            gload16(Abh + go, &Ash[r * 2048 + wb8]);
            gload16(Bbh + go, &Bsh[r * 2048 + wb8]);
            gload16(Bbl + go, &Bsl[r * 2048 + wb8]);
        }
        __syncthreads();
#pragma unroll
        for (int ks = 0; ks < 2; ++ks) {
            bf16x8 afh[4], bfh[4], bfl[4];
#pragma unroll
            for (int mi = 0; mi < 4; ++mi) {
                const int off = (wr * 64 + mi * 16 + lr) * 64 + ks * 32 + lg * 8;
                afh[mi] = *(const bf16x8*)&Ash[off];
            }
#pragma unroll
            for (int ni = 0; ni < 4; ++ni) {
                const int off = (wc * 64 + ni * 16 + lr) * 64 + ks * 32 + lg * 8;
                bfh[ni] = *(const bf16x8*)&Bsh[off];
                bfl[ni] = *(const bf16x8*)&Bsl[off];
            }
#pragma unroll
            for (int mi = 0; mi < 4; ++mi)
#pragma unroll
                for (int ni = 0; ni < 4; ++ni) {
                    mfma16(acc[mi][ni], afh[mi], bfh[ni]);
                    mfma16(acc[mi][ni], afh[mi], bfl[ni]);
                }
        }
        __syncthreads();
    }

#pragma unroll
    for (int ni = 0; ni < 4; ++ni) {
        const int col = bcol + wc * 64 + ni * 16 + lr;
        const float bval = bias0[col];
#pragma unroll
        for (int mi = 0; mi < 4; ++mi) {
#pragma unroll
            for (int j = 0; j < 4; ++j) {
                const int row = brow + wr * 64 + mi * 16 + lg * 4 + j;
                float v = acc[mi][ni][j] + bval;
                if constexpr (MODE == 3) {
                    ((float*)out0)[(size_t)row * N + col] = v + res[(size_t)row * N + col];
                } else if constexpr (MODE == 4) {
                    const float u = 0.7978845608028654f * (v + 0.044715f * v * v * v);
                    const float g = 0.5f * v * (1.0f + tanhf(u));
                    ((bf16*)out0)[(size_t)row * N + col] = (bf16)g;
                }
            }
        }
    }
}

// =======================================================================
// gemm_bt1 (R14-verbatim): C = Ah[M][K] * Bh[N][K]^T; 32KB LDS.
// MODE 3: fp32 out0 = acc + bias0[n] + res[m][n]
// MODE 4: bf16 out0 = gelu_tanh(acc + bias0[n])
// =======================================================================
template <int MODE>
__global__ __launch_bounds__(256) void gemm_bt1(
    const bf16* __restrict__ Ah,
    const bf16* __restrict__ Bh,
    const float* __restrict__ bias0, const float* __restrict__ res,
    void* __restrict__ out0, int M, int N, int K) {
    __shared__ alignas(16) bf16 Ash[128 * 64];
    __shared__ alignas(16) bf16 Bsh[128 * 64];
    const int t  = threadIdx.x;
    const int l  = t & 63;
    const int w  = t >> 6;
    const int wr = w >> 1, wc = w & 1;
    const int lg = l >> 4, lr = l & 15;
    const int nwg  = gridDim.x * gridDim.y;
    const int bidl = blockIdx.y * gridDim.x + blockIdx.x;
    const int swz  = (bidl & 7) * (nwg >> 3) + (bidl >> 3);
    const int brow = (swz / gridDim.x) * 128;
    const int bcol = (swz % gridDim.x) * 128;

    f32x4 acc[4][4] = {};
    const bf16* Abh = Ah + (size_t)brow * K;
    const bf16* Bbh = Bh + (size_t)bcol * K;
    const int wb8 = (t & ~63) * 8;

    for (int kt = 0; kt < K; kt += 64) {
#pragma unroll
        for (int r = 0; r < 4; ++r) {
            const int e = (r * 256 + t) * 8;
            const int row = e >> 6, col = e & 63;
            const size_t go = (size_t)row * K + kt + col;
            gload16(Abh + go, &Ash[r * 2048 + wb8]);
            gload16(Bbh + go, &Bsh[r * 2048 + wb8]);
        }
        __syncthreads();
#pragma unroll
        for (int ks = 0; ks < 2; ++ks) {
            bf16x8 afh[4], bfh[4];
#pragma unroll
            for (int mi = 0; mi < 4; ++mi) {
                const int off = (wr * 64 + mi * 16 + lr) * 64 + ks * 32 + lg * 8;
                afh[mi] = *(const bf16x8*)&Ash[off];
            }
#pragma unroll
            for (int ni = 0; ni < 4; ++ni) {
                const int off = (wc * 64 + ni * 16 + lr) * 64 + ks * 32 + lg * 8;
                bfh[ni] = *(const bf16x8*)&Bsh[off];
            }
#pragma unroll
            for (int mi = 0; mi < 4; ++mi)
#pragma unroll
                for (int ni = 0; ni < 4; ++ni) {
                    mfma16(acc[mi][ni], afh[mi], bfh[ni]);
                }
        }
        __syncthreads();
    }

#pragma unroll
    for (int ni = 0; ni < 4; ++ni) {
        const int col = bcol + wc * 64 + ni * 16 + lr;
        const float bval = bias0[col];
#pragma unroll
        for (int mi = 0; mi < 4; ++mi) {
#pragma unroll
            for (int j = 0; j < 4; ++j) {
                const int row = brow + wr * 64 + mi * 16 + lg * 4 + j;
                float v = acc[mi][ni][j] + bval;
                if constexpr (MODE == 3) {
                    ((float*)out0)[(size_t)row * N + col] = v + res[(size_t)row * N + col];
                } else if constexpr (MODE == 4) {
                    const float u = 0.7978845608028654f * (v + 0.044715f * v * v * v);
                    const float g = 0.5f * v * (1.0f + tanhf(u));
                    ((bf16*)out0)[(size_t)row * N + col] = (bf16)g;
                }
            }
        }
    }
}

// =======================================================================
// Causal flash attention, split-precision Q/K/P/V — R11-VERBATIM (frozen).
// R7 body + R9 mapping (complementary qt pairing + XCD-local bh).
// The P-LDS two-plane path is load-bearing: every variant that touched it
// (R3/R4/R5/R6/R8/R12) failed; do not modify.
// =======================================================================
__global__ __launch_bounds__(256) void attn_kernel(
    const bf16* __restrict__ qh, const bf16* __restrict__ ql,
    const bf16* __restrict__ kh, const bf16* __restrict__ kl,
    const bf16* __restrict__ vth, const bf16* __restrict__ vtl,
    bf16* __restrict__ oh, bf16* __restrict__ ol) {
    __shared__ alignas(16) bf16 Ksh[64 * 64], Ksl[64 * 64];
    __shared__ alignas(16) bf16 Vsh[64 * 64], Vsl[64 * 64];   // [hd][kv]
    __shared__ alignas(16) bf16 Psh[4][32 * 64], Psl[4][32 * 64];
    const int bid = blockIdx.x;                 // 0..511
    const int qtidx = (bid >> 3) & 15;
    const int qt = (bid & 256) ? (15 - qtidx) : qtidx;  // complementary pairing
    const int bh = (bid & 7) + 8 * (bid >> 7);  // head-group -> fixed XCD slot
    const int b = bh >> 4, h = bh & 15;
    const int t = threadIdx.x;
    const int w = t >> 6, l = t & 63;
    const int lg = l >> 4, lr = l & 15;
    const int qrow0 = qt * 128 + w * 32;
    const size_t tokbase = (size_t)b * SEQ;

    bf16x8 qfh[2][2], qfl[2][2];
#pragma unroll
    for (int mi = 0; mi < 2; ++mi)
#pragma unroll
        for (int ks = 0; ks < 2; ++ks) {
            const size_t off = (tokbase + qrow0 + mi * 16 + lr) * DM + h * HD + ks * 32 + lg * 8;
            qfh[mi][ks] = *(const bf16x8*)&qh[off];
            qfl[mi][ks] = *(const bf16x8*)&ql[off];
        }

    f32x4 oacc[2][4] = {};
    float mrow[2][4], lrow[2][4];
#pragma unroll
    for (int mi = 0; mi < 2; ++mi)
#pragma unroll
        for (int j = 0; j < 4; ++j) { mrow[mi][j] = -1e30f; lrow[mi][j] = 0.f; }

    const int wb8 = (t & ~63) * 8;
    const int nkv = 2 * (qt + 1);
    for (int kt = 0; kt < nkv; ++kt) {
#pragma unroll
        for (int r = 0; r < 2; ++r) {
            const int e = (r * 256 + t) * 8;
            const int rr = e >> 6, cc = e & 63;
            const size_t kg = (tokbase + kt * 64 + rr) * DM + h * HD + cc;
            const size_t vg = (((size_t)((b * NH + h) * HD + rr)) << 11) + kt * 64 + cc;
            gload16(&kh[kg], &Ksh[r * 2048 + wb8]);
            gload16(&kl[kg], &Ksl[r * 2048 + wb8]);
            gload16(&vth[vg], &Vsh[r * 2048 + wb8]);
            gload16(&vtl[vg], &Vsl[r * 2048 + wb8]);
        }
        __syncthreads();
        const bool active = (kt * 64 <= qrow0 + 31);
        if (active) {
            f32x4 sf[2][4] = {};
#pragma unroll
            for (int ks = 0; ks < 2; ++ks)
#pragma unroll
                for (int ni = 0; ni < 4; ++ni) {
                    const int off = (ni * 16 + lr) * 64 + ks * 32 + lg * 8;
                    const bf16x8 kfh = *(const bf16x8*)&Ksh[off];
                    const bf16x8 kfl = *(const bf16x8*)&Ksl[off];
#pragma unroll
                    for (int mi = 0; mi < 2; ++mi) {
                        mfma16(sf[mi][ni], qfh[mi][ks], kfh);
                        mfma16(sf[mi][ni], qfh[mi][ks], kfl);
                        mfma16(sf[mi][ni], qfl[mi][ks], kfh);
                    }
                }
#pragma unroll
            for (int mi = 0; mi < 2; ++mi)
#pragma unroll
                for (int ni = 0; ni < 4; ++ni)
#pragma unroll
                    for (int j = 0; j < 4; ++j) {
                        const float sv = sf[mi][ni][j] * 0.125f;
                        const int qg = qrow0 + mi * 16 + lg * 4 + j;
                        const int kg = kt * 64 + ni * 16 + lr;
                        sf[mi][ni][j] = (kg > qg) ? -1e30f : sv;
                    }
#pragma unroll
            for (int mi = 0; mi < 2; ++mi)
#pragma unroll
                for (int j = 0; j < 4; ++j) {
                    float pm = fmaxf(fmaxf(sf[mi][0][j], sf[mi][1][j]),
                                     fmaxf(sf[mi][2][j], sf[mi][3][j]));
#pragma unroll
                    for (int msk = 1; msk <= 8; msk <<= 1)
                        pm = fmaxf(pm, __shfl_xor(pm, msk));
                    const float mnew = fmaxf(mrow[mi][j], pm);
                    const float resc = __expf(mrow[mi][j] - mnew);
                    mrow[mi][j] = mnew;
                    float rsum = 0.f;
#pragma unroll
                    for (int ni = 0; ni < 4; ++ni) {
                        const float p = __expf(sf[mi][ni][j] - mnew);
                        sf[mi][ni][j] = p;
                        rsum += p;
                    }
#pragma unroll
                    for (int msk = 1; msk <= 8; msk <<= 1)
                        rsum += __shfl_xor(rsum, msk);
                    lrow[mi][j] = lrow[mi][j] * resc + rsum;
#pragma unroll
                    for (int di = 0; di < 4; ++di) oacc[mi][di][j] *= resc;
                }
#pragma unroll
            for (int mi = 0; mi < 2; ++mi)
#pragma unroll
                for (int ni = 0; ni < 4; ++ni)
#pragma unroll
                    for (int j = 0; j < 4; ++j) {
                        const float p = sf[mi][ni][j];
                        const int idx = (mi * 16 + lg * 4 + j) * 64 + ni * 16 + lr;
                        bf16 hh, lo2; split2(p, hh, lo2);
                        Psh[w][idx] = hh;
                        Psl[w][idx] = lo2;
                    }
#pragma unroll
            for (int ks = 0; ks < 2; ++ks) {
                bf16x8 pah[2], pal[2];
#pragma unroll
                for (int mi = 0; mi < 2; ++mi) {
                    const int off = (mi * 16 + lr) * 64 + ks * 32 + lg * 8;
                    pah[mi] = *(const bf16x8*)&Psh[w][off];
                    pal[mi] = *(const bf16x8*)&Psl[w][off];
                }
#pragma unroll
                for (int di = 0; di < 4; ++di) {
                    const int off = (di * 16 + lr) * 64 + ks * 32 + lg * 8;
                    const bf16x8 vfh = *(const bf16x8*)&Vsh[off];
                    const bf16x8 vfl = *(const bf16x8*)&Vsl[off];
#pragma unroll
                    for (int mi = 0; mi < 2; ++mi) {
                        mfma16(oacc[mi][di], pah[mi], vfh);
                        mfma16(oacc[mi][di], pah[mi], vfl);
                        mfma16(oacc[mi][di], pal[mi], vfh);
                    }
                }
            }
        }
        __syncthreads();
    }
#pragma unroll
    for (int mi = 0; mi < 2; ++mi)
#pragma unroll
        for (int j = 0; j < 4; ++j) {
            const float inv = 1.0f / lrow[mi][j];
            const int row = qrow0 + mi * 16 + lg * 4 + j;
#pragma unroll
            for (int di = 0; di < 4; ++di) {
                const float f = oacc[mi][di][j] * inv;
                bf16 hh, lo2; split2(f, hh, lo2);
                const size_t idx = (tokbase + row) * DM + h * HD + di * 16 + lr;
                oh[idx] = hh;
                ol[idx] = lo2;
            }
        }
}

// =======================================================================
extern "C" void kernel_launch(void* const* d_in, const int* in_sizes, int n_in,
                              void* d_out, int out_size, void* d_ws, size_t ws_size,
                              hipStream_t stream) {
    const float* x    = (const float*)d_in[0];
    const float* ln1s = (const float*)d_in[2];
    const float* ln1b = (const float*)d_in[3];
    const float* Wq   = (const float*)d_in[4];
    const float* bq   = (const float*)d_in[5];
    const float* Wk   = (const float*)d_in[6];
    const float* bk   = (const float*)d_in[7];
    const float* Wv   = (const float*)d_in[8];
    const float* bv   = (const float*)d_in[9];
    const float* Wo   = (const float*)d_in[10];
    const float* bo   = (const float*)d_in[11];
    const float* ln2s = (const float*)d_in[12];
    const float* ln2b = (const float*)d_in[13];
    const float* W1   = (const float*)d_in[14];
    const float* b1   = (const float*)d_in[15];
    const float* W2   = (const float*)d_in[16];
    const float* b2   = (const float*)d_in[17];
    float* out = (float*)d_out;

    const size_t M1 = (size_t)1024 * 1024;  // 1M elems
    bf16* ws = (bf16*)d_ws;
    // weights
    bf16* Wqkv_h = ws;                 // 3M (hi only now)
    bf16* Wo_h   = ws + 6 * M1;
    bf16* Wo_l   = ws + 7 * M1;
    bf16* W1_h   = ws + 8 * M1;        // 4M (hi only)
    bf16* W2_h   = ws + 16 * M1;       // 4M (hi only)
    // activations
    bf16*  xn_h  = ws + 24 * M1;       // 4M (hi only)
    float* x1    = (float*)(ws + 32 * M1);  // 4M fp32 (8M slots)
    bf16*  q_h   = ws + 40 * M1;
    bf16*  q_l   = ws + 44 * M1;
    bf16*  k_h   = ws + 48 * M1;
    bf16*  k_l   = ws + 52 * M1;
    bf16*  vt_h  = ws + 56 * M1;
    bf16*  vt_l  = ws + 60 * M1;
    bf16*  o_h   = ws + 64 * M1;
    bf16*  o_l   = ws + 68 * M1;       // written by frozen attn (o_l unused downstream)
    // MLP hidden (hi only) overlays q..o region (dead after O-proj)
    bf16*  h_h   = ws + 40 * M1;       // 16M

    const dim3 blk(256);
    transpose_convert_h<<<dim3(32, 32), blk, 0, stream>>>(Wq, Wqkv_h,        1024, 1024);
    transpose_convert_h<<<dim3(32, 32), blk, 0, stream>>>(Wk, Wqkv_h + M1,   1024, 1024);
    transpose_convert_h<<<dim3(32, 32), blk, 0, stream>>>(Wv, Wqkv_h + 2*M1, 1024, 1024);
    transpose_convert<<<dim3(32, 32), blk, 0, stream>>>(Wo, Wo_h, Wo_l, 1024, 1024);
    transpose_convert_h<<<dim3(128, 32), blk, 0, stream>>>(W1, W1_h, 1024, 4096);
    transpose_convert_h<<<dim3(32, 128), blk, 0, stream>>>(W2, W2_h, 4096, 1024);

    layernorm_h<<<NTOK, blk, 0, stream>>>(x, ln1s, ln1b, xn_h);

    // fused QKV: plain bf16 x plain bf16 (B-lo deletion, 32KB LDS)
    gemm_bt5b<<<dim3(24, 32), blk, 0, stream>>>(xn_h, Wqkv_h,
        bq, bk, bv, q_h, k_h, vt_h, 4 * M1, NTOK, 3072, 1024);

    attn_kernel<<<512, blk, 0, stream>>>(q_h, q_l, k_h, k_l, vt_h, vt_l, o_h, o_l);

    // O projection + residual: A hi-only x split Wo
    gemm_bt2<3><<<dim3(8, 32), blk, 0, stream>>>(o_h, Wo_h, Wo_l,
        bo, x, x1, NTOK, 1024, 1024);

    layernorm_h<<<NTOK, blk, 0, stream>>>(x1, ln2s, ln2b, xn_h);

    // MLP up + GELU
    gemm_bt1<4><<<dim3(32, 32), blk, 0, stream>>>(xn_h, W1_h,
        b1, nullptr, h_h, NTOK, DFF, 1024);

    // MLP down + residual -> out
    gemm_bt1<3><<<dim3(8, 32), blk, 0, stream>>>(h_h, W2_h,
        b2, x1, out, NTOK, 1024, DFF);
}

// Round 16
// 400.423 us; speedup vs baseline: 1.5168x; 1.0027x over previous
//
#include <hip/hip_runtime.h>
#include <cmath>

#define DM   1024
#define DFF  4096
#define NH   16
#define HD   64
#define SEQ  2048
#define NB   2
#define NTOK (NB * SEQ)  // 4096

typedef __bf16 bf16;
typedef __bf16 bf16x8 __attribute__((ext_vector_type(8)));
typedef float  f32x4  __attribute__((ext_vector_type(4)));

// ---- MFMA via inline asm ----
__device__ __forceinline__ void mfma16(f32x4& acc, bf16x8 a, bf16x8 b) {
    asm("v_mfma_f32_16x16x32_bf16 %0, %1, %2, %0" : "+v"(acc) : "v"(a), "v"(b));
}
// ---- async global->LDS, 16B/lane; LDS base must be wave-uniform ----
__device__ __forceinline__ void gload16(const void* g, void* l) {
    __builtin_amdgcn_global_load_lds(
        (__attribute__((address_space(1))) void*)(void*)g,
        (__attribute__((address_space(3))) void*)l, 16, 0, 0);
}
// ---- fp32 -> (hi, lo) bf16 pair; hi+lo ~ 16-bit-mantissa accurate ----
__device__ __forceinline__ void split2(float v, bf16& h, bf16& l) {
    h = (bf16)v; l = (bf16)(v - (float)h);
}

// =======================================================================
// Weight transpose + fp32 -> split bf16:  W[K][N] -> Wth/Wtl [N][K]
// (retained; unused)
// =======================================================================
__global__ __launch_bounds__(256) void transpose_convert(
    const float* __restrict__ W, bf16* __restrict__ Wth, bf16* __restrict__ Wtl,
    int K, int N) {
    __shared__ float tile[32][33];
    const int bn = blockIdx.x * 32;
    const int bk = blockIdx.y * 32;
    const int tx = threadIdx.x & 31;
    const int ty = (threadIdx.x >> 5) << 2;
#pragma unroll
    for (int i = 0; i < 4; ++i)
        tile[ty + i][tx] = W[(size_t)(bk + ty + i) * N + bn + tx];
    __syncthreads();
#pragma unroll
    for (int i = 0; i < 4; ++i) {
        const float v = tile[tx][ty + i];
        bf16 h, l; split2(v, h, l);
        Wth[(size_t)(bn + ty + i) * K + bk + tx] = h;
        Wtl[(size_t)(bn + ty + i) * K + bk + tx] = l;
    }
}

// =======================================================================
// transpose_convert_h: lo-plane store deleted (hi only).
// =======================================================================
__global__ __launch_bounds__(256) void transpose_convert_h(
    const float* __restrict__ W, bf16* __restrict__ Wth, int K, int N) {
    __shared__ float tile[32][33];
    const int bn = blockIdx.x * 32;
    const int bk = blockIdx.y * 32;
    const int tx = threadIdx.x & 31;
    const int ty = (threadIdx.x >> 5) << 2;
#pragma unroll
    for (int i = 0; i < 4; ++i)
        tile[ty + i][tx] = W[(size_t)(bk + ty + i) * N + bn + tx];
    __syncthreads();
#pragma unroll
    for (int i = 0; i < 4; ++i)
        Wth[(size_t)(bn + ty + i) * K + bk + tx] = (bf16)tile[tx][ty + i];
}

// =======================================================================
// layernorm_h: fp32 in -> bf16 out (hi only).
// =======================================================================
__global__ __launch_bounds__(256) void layernorm_h(
    const float* __restrict__ x, const float* __restrict__ scale,
    const float* __restrict__ bias, bf16* __restrict__ oh) {
    const int row = blockIdx.x;
    const int t = threadIdx.x;
    const float4 v = ((const float4*)(x + (size_t)row * DM))[t];
    float s  = v.x + v.y + v.z + v.w;
    float ss = v.x * v.x + v.y * v.y + v.z * v.z + v.w * v.w;
#pragma unroll
    for (int m = 1; m < 64; m <<= 1) {
        s  += __shfl_xor(s, m);
        ss += __shfl_xor(ss, m);
    }
    __shared__ float red[2][4];
    const int w = t >> 6;
    if ((t & 63) == 0) { red[0][w] = s; red[1][w] = ss; }
    __syncthreads();
    s  = red[0][0] + red[0][1] + red[0][2] + red[0][3];
    ss = red[1][0] + red[1][1] + red[1][2] + red[1][3];
    const float mu = s * (1.0f / DM);
    const float rs = rsqrtf(ss * (1.0f / DM) - mu * mu + 1e-6f);
    const float4 sc = ((const float4*)scale)[t];
    const float4 bi = ((const float4*)bias)[t];
    const float y[4] = {(v.x - mu) * rs * sc.x + bi.x, (v.y - mu) * rs * sc.y + bi.y,
                        (v.z - mu) * rs * sc.z + bi.z, (v.w - mu) * rs * sc.w + bi.w};
    bf16 o0, o1, o2, o3;
    o0 = (bf16)y[0]; o1 = (bf16)y[1]; o2 = (bf16)y[2]; o3 = (bf16)y[3];
    bf16* dst = oh + (size_t)row * DM + t * 4;
    dst[0] = o0; dst[1] = o1; dst[2] = o2; dst[3] = o3;
}

// =======================================================================
// gemm_bt5b (R15-verbatim): fused QKV, C = Ah * Bh^T, 32KB LDS.
// Epilogue: q(out0)/k(out1) split planes, v^T(out2) split planes.
// =======================================================================
__global__ __launch_bounds__(256) void gemm_bt5b(
    const bf16* __restrict__ Ah,
    const bf16* __restrict__ Bh,
    const float* __restrict__ bias0, const float* __restrict__ bias1,
    const float* __restrict__ bias2,
    void* __restrict__ out0, void* __restrict__ out1, void* __restrict__ out2,
    size_t loStride, int M, int N, int K) {
    __shared__ alignas(16) bf16 Ash[128 * 64];
    __shared__ alignas(16) bf16 Bsh[128 * 64];
    const int t  = threadIdx.x;
    const int l  = t & 63;
    const int w  = t >> 6;
    const int wr = w >> 1, wc = w & 1;
    const int lg = l >> 4, lr = l & 15;
    const int nwg  = gridDim.x * gridDim.y;
    const int bidl = blockIdx.y * gridDim.x + blockIdx.x;
    const int swz  = (bidl & 7) * (nwg >> 3) + (bidl >> 3);
    const int brow = (swz / gridDim.x) * 128;
    const int bcol = (swz % gridDim.x) * 128;

    f32x4 acc[4][4] = {};
    const bf16* Abh = Ah + (size_t)brow * K;
    const bf16* Bbh = Bh + (size_t)bcol * K;
    const int wb8 = (t & ~63) * 8;

    for (int kt = 0; kt < K; kt += 64) {
#pragma unroll
        for (int r = 0; r < 4; ++r) {
            const int e = (r * 256 + t) * 8;
            const int row = e >> 6, col = e & 63;
            const size_t go = (size_t)row * K + kt + col;
            gload16(Abh + go, &Ash[r * 2048 + wb8]);
            gload16(Bbh + go, &Bsh[r * 2048 + wb8]);
        }
        __syncthreads();
#pragma unroll
        for (int ks = 0; ks < 2; ++ks) {
            bf16x8 afh[4], bfh[4];
#pragma unroll
            for (int mi = 0; mi < 4; ++mi) {
                const int off = (wr * 64 + mi * 16 + lr) * 64 + ks * 32 + lg * 8;
                afh[mi] = *(const bf16x8*)&Ash[off];
            }
#pragma unroll
            for (int ni = 0; ni < 4; ++ni) {
                const int off = (wc * 64 + ni * 16 + lr) * 64 + ks * 32 + lg * 8;
                bfh[ni] = *(const bf16x8*)&Bsh[off];
            }
#pragma unroll
            for (int mi = 0; mi < 4; ++mi)
#pragma unroll
                for (int ni = 0; ni < 4; ++ni) {
                    mfma16(acc[mi][ni], afh[mi], bfh[ni]);
                }
        }
        __syncthreads();
    }

#pragma unroll
    for (int ni = 0; ni < 4; ++ni) {
        const int col = bcol + wc * 64 + ni * 16 + lr;
        const int sub = col >> 10;
        const int nn = col & 1023;
        const float* bp = (sub == 0) ? bias0 : (sub == 1 ? bias1 : bias2);
        const float bval = bp[nn];
#pragma unroll
        for (int mi = 0; mi < 4; ++mi) {
#pragma unroll
            for (int j = 0; j < 4; ++j) {
                const int row = brow + wr * 64 + mi * 16 + lg * 4 + j;
                float v = acc[mi][ni][j] + bval;
                bf16 h, lo2; split2(v, h, lo2);
                if (sub < 2) {
                    bf16* dst = (bf16*)(sub == 0 ? out0 : out1);
                    dst[(size_t)row * DM + nn] = h;
                    dst[(size_t)row * DM + nn + loStride] = lo2;
                } else {
                    const int bb = row >> 11, sI = row & (SEQ - 1);
                    const int hh = nn >> 6, d = nn & 63;
                    const size_t idx = (((size_t)((bb * NH + hh) * HD + d)) << 11) + sI;
                    ((bf16*)out2)[idx] = h;
                    ((bf16*)out2)[idx + loStride] = lo2;
                }
            }
        }
    }
}

// =======================================================================
// gemm_bt2 (R11-verbatim, retained; unused): C = Ah * (Bh+Bl)^T; 48KB LDS.
// =======================================================================
template <int MODE>
__global__ __launch_bounds__(256) void gemm_bt2(
    const bf16* __restrict__ Ah,
    const bf16* __restrict__ Bh, const bf16* __restrict__ Bl,
    const float* __restrict__ bias0, const float* __restrict__ res,
    void* __restrict__ out0, int M, int N, int K) {
    __shared__ alignas(16) bf16 Ash[128 * 64];
    __shared__ alignas(16) bf16 Bsh[128 * 64];
    __shared__ alignas(16) bf16 Bsl[128 * 64];
    const int t  = threadIdx.x;
    const int l  = t & 63;
    const int w  = t >> 6;
    const int wr = w >> 1, wc = w & 1;
    const int lg = l >> 4, lr = l & 15;
    const int nwg  = gridDim.x * gridDim.y;
    const int bidl = blockIdx.y * gridDim.x + blockIdx.x;
    const int swz  = (bidl & 7) * (nwg >> 3) + (bidl >> 3);
    const int brow = (swz / gridDim.x) * 128;
    const int bcol = (swz % gridDim.x) * 128;

    f32x4 acc[4][4] = {};
    const bf16* Abh = Ah + (size_t)brow * K;
    const bf16* Bbh = Bh + (size_t)bcol * K;
    const bf16* Bbl = Bl + (size_t)bcol * K;
    const int wb8 = (t & ~63) * 8;

    for (int kt = 0; kt < K; kt += 64) {
#pragma unroll
        for (int r = 0; r < 4; ++r) {
            const int e = (r * 256 + t) * 8;
            const int row = e >> 6, col = e & 63;
            const size_t go = (size_t)row * K + kt + col;
            gload16(Abh + go, &Ash[r * 2048 + wb8]);
            gload16(Bbh + go, &Bsh[r * 2048 + wb8]);
            gload16(Bbl + go, &Bsl[r * 2048 + wb8]);
        }
        __syncthreads();
#pragma unroll
        for (int ks = 0; ks < 2; ++ks) {
            bf16x8 afh[4], bfh[4], bfl[4];
#pragma unroll
            for (int mi = 0; mi < 4; ++mi) {
                const int off = (wr * 64 + mi * 16 + lr) * 64 + ks * 32 + lg * 8;
                afh[mi] = *(const bf16x8*)&Ash[off];
            }
#pragma unroll
            for (int ni = 0; ni < 4; ++ni) {
                const int off = (wc * 64 + ni * 16 + lr) * 64 + ks * 32 + lg * 8;
                bfh[ni] = *(const bf16x8*)&Bsh[off];
                bfl[ni] = *(const bf16x8*)&Bsl[off];
            }
#pragma unroll
            for (int mi = 0; mi < 4; ++mi)
#pragma unroll
                for (int ni = 0; ni < 4; ++ni) {
                    mfma16(acc[mi][ni], afh[mi], bfh[ni]);
                    mfma16(acc[mi][ni], afh[mi], bfl[ni]);
                }
        }
        __syncthreads();
    }

#pragma unroll
    for (int ni = 0; ni < 4; ++ni) {
        const int col = bcol + wc * 64 + ni * 16 + lr;
        const float bval = bias0[col];
#pragma unroll
        for (int mi = 0; mi < 4; ++mi) {
#pragma unroll
            for (int j = 0; j < 4; ++j) {
                const int row = brow + wr * 64 + mi * 16 + lg * 4 + j;
                float v = acc[mi][ni][j] + bval;
                if constexpr (MODE == 3) {
                    ((float*)out0)[(size_t)row * N + col] = v + res[(size_t)row * N + col];
                } else if constexpr (MODE == 4) {
                    const float u = 0.7978845608028654f * (v + 0.044715f * v * v * v);
                    const float g = 0.5f * v * (1.0f + tanhf(u));
                    ((bf16*)out0)[(size_t)row * N + col] = (bf16)g;
                }
            }
        }
    }
}

// =======================================================================
// gemm_bt1 (R14-verbatim): C = Ah[M][K] * Bh[N][K]^T; 32KB LDS.
// MODE 3: fp32 out0 = acc + bias0[n] + res[m][n]
// MODE 4: bf16 out0 = gelu_tanh(acc + bias0[n])
// =======================================================================
template <int MODE>
__global__ __launch_bounds__(256) void gemm_bt1(
    const bf16* __restrict__ Ah,
    const bf16* __restrict__ Bh,
    const float* __restrict__ bias0, const float* __restrict__ res,
    void* __restrict__ out0, int M, int N, int K) {
    __shared__ alignas(16) bf16 Ash[128 * 64];
    __shared__ alignas(16) bf16 Bsh[128 * 64];
    const int t  = threadIdx.x;
    const int l  = t & 63;
    const int w  = t >> 6;
    const int wr = w >> 1, wc = w & 1;
    const int lg = l >> 4, lr = l & 15;
    const int nwg  = gridDim.x * gridDim.y;
    const int bidl = blockIdx.y * gridDim.x + blockIdx.x;
    const int swz  = (bidl & 7) * (nwg >> 3) + (bidl >> 3);
    const int brow = (swz / gridDim.x) * 128;
    const int bcol = (swz % gridDim.x) * 128;

    f32x4 acc[4][4] = {};
    const bf16* Abh = Ah + (size_t)brow * K;
    const bf16* Bbh = Bh + (size_t)bcol * K;
    const int wb8 = (t & ~63) * 8;

    for (int kt = 0; kt < K; kt += 64) {
#pragma unroll
        for (int r = 0; r < 4; ++r) {
            const int e = (r * 256 + t) * 8;
            const int row = e >> 6, col = e & 63;
            const size_t go = (size_t)row * K + kt + col;
            gload16(Abh + go, &Ash[r * 2048 + wb8]);
            gload16(Bbh + go, &Bsh[r * 2048 + wb8]);
        }
        __syncthreads();
#pragma unroll
        for (int ks = 0; ks < 2; ++ks) {
            bf16x8 afh[4], bfh[4];
#pragma unroll
            for (int mi = 0; mi < 4; ++mi) {
                const int off = (wr * 64 + mi * 16 + lr) * 64 + ks * 32 + lg * 8;
                afh[mi] = *(const bf16x8*)&Ash[off];
            }
#pragma unroll
            for (int ni = 0; ni < 4; ++ni) {
                const int off = (wc * 64 + ni * 16 + lr) * 64 + ks * 32 + lg * 8;
                bfh[ni] = *(const bf16x8*)&Bsh[off];
            }
#pragma unroll
            for (int mi = 0; mi < 4; ++mi)
#pragma unroll
                for (int ni = 0; ni < 4; ++ni) {
                    mfma16(acc[mi][ni], afh[mi], bfh[ni]);
                }
        }
        __syncthreads();
    }

#pragma unroll
    for (int ni = 0; ni < 4; ++ni) {
        const int col = bcol + wc * 64 + ni * 16 + lr;
        const float bval = bias0[col];
#pragma unroll
        for (int mi = 0; mi < 4; ++mi) {
#pragma unroll
            for (int j = 0; j < 4; ++j) {
                const int row = brow + wr * 64 + mi * 16 + lg * 4 + j;
                float v = acc[mi][ni][j] + bval;
                if constexpr (MODE == 3) {
                    ((float*)out0)[(size_t)row * N + col] = v + res[(size_t)row * N + col];
                } else if constexpr (MODE == 4) {
                    const float u = 0.7978845608028654f * (v + 0.044715f * v * v * v);
                    const float g = 0.5f * v * (1.0f + tanhf(u));
                    ((bf16*)out0)[(size_t)row * N + col] = (bf16)g;
                }
            }
        }
    }
}

// =======================================================================
// Causal flash attention, split-precision Q/K/P/V — R11-VERBATIM (frozen).
// R7 body + R9 mapping (complementary qt pairing + XCD-local bh).
// The P-LDS two-plane path is load-bearing: every variant that touched it
// (R3/R4/R5/R6/R8/R12) failed; do not modify.
// =======================================================================
__global__ __launch_bounds__(256) void attn_kernel(
    const bf16* __restrict__ qh, const bf16* __restrict__ ql,
    const bf16* __restrict__ kh, const bf16* __restrict__ kl,
    const bf16* __restrict__ vth, const bf16* __restrict__ vtl,
    bf16* __restrict__ oh, bf16* __restrict__ ol) {
    __shared__ alignas(16) bf16 Ksh[64 * 64], Ksl[64 * 64];
    __shared__ alignas(16) bf16 Vsh[64 * 64], Vsl[64 * 64];   // [hd][kv]
    __shared__ alignas(16) bf16 Psh[4][32 * 64], Psl[4][32 * 64];
    const int bid = blockIdx.x;                 // 0..511
    const int qtidx = (bid >> 3) & 15;
    const int qt = (bid & 256) ? (15 - qtidx) : qtidx;  // complementary pairing
    const int bh = (bid & 7) + 8 * (bid >> 7);  // head-group -> fixed XCD slot
    const int b = bh >> 4, h = bh & 15;
    const int t = threadIdx.x;
    const int w = t >> 6, l = t & 63;
    const int lg = l >> 4, lr = l & 15;
    const int qrow0 = qt * 128 + w * 32;
    const size_t tokbase = (size_t)b * SEQ;

    bf16x8 qfh[2][2], qfl[2][2];
#pragma unroll
    for (int mi = 0; mi < 2; ++mi)
#pragma unroll
        for (int ks = 0; ks < 2; ++ks) {
            const size_t off = (tokbase + qrow0 + mi * 16 + lr) * DM + h * HD + ks * 32 + lg * 8;
            qfh[mi][ks] = *(const bf16x8*)&qh[off];
            qfl[mi][ks] = *(const bf16x8*)&ql[off];
        }

    f32x4 oacc[2][4] = {};
    float mrow[2][4], lrow[2][4];
#pragma unroll
    for (int mi = 0; mi < 2; ++mi)
#pragma unroll
        for (int j = 0; j < 4; ++j) { mrow[mi][j] = -1e30f; lrow[mi][j] = 0.f; }

    const int wb8 = (t & ~63) * 8;
    const int nkv = 2 * (qt + 1);
    for (int kt = 0; kt < nkv; ++kt) {
#pragma unroll
        for (int r = 0; r < 2; ++r) {
            const int e = (r * 256 + t) * 8;
            const int rr = e >> 6, cc = e & 63;
            const size_t kg = (tokbase + kt * 64 + rr) * DM + h * HD + cc;
            const size_t vg = (((size_t)((b * NH + h) * HD + rr)) << 11) + kt * 64 + cc;
            gload16(&kh[kg], &Ksh[r * 2048 + wb8]);
            gload16(&kl[kg], &Ksl[r * 2048 + wb8]);
            gload16(&vth[vg], &Vsh[r * 2048 + wb8]);
            gload16(&vtl[vg], &Vsl[r * 2048 + wb8]);
        }
        __syncthreads();
        const bool active = (kt * 64 <= qrow0 + 31);
        if (active) {
            f32x4 sf[2][4] = {};
#pragma unroll
            for (int ks = 0; ks < 2; ++ks)
#pragma unroll
                for (int ni = 0; ni < 4; ++ni) {
                    const int off = (ni * 16 + lr) * 64 + ks * 32 + lg * 8;
                    const bf16x8 kfh = *(const bf16x8*)&Ksh[off];
                    const bf16x8 kfl = *(const bf16x8*)&Ksl[off];
#pragma unroll
                    for (int mi = 0; mi < 2; ++mi) {
                        mfma16(sf[mi][ni], qfh[mi][ks], kfh);
                        mfma16(sf[mi][ni], qfh[mi][ks], kfl);
                        mfma16(sf[mi][ni], qfl[mi][ks], kfh);
                    }
                }
#pragma unroll
            for (int mi = 0; mi < 2; ++mi)
#pragma unroll
                for (int ni = 0; ni < 4; ++ni)
#pragma unroll
                    for (int j = 0; j < 4; ++j) {
                        const float sv = sf[mi][ni][j] * 0.125f;
                        const int qg = qrow0 + mi * 16 + lg * 4 + j;
                        const int kg = kt * 64 + ni * 16 + lr;
                        sf[mi][ni][j] = (kg > qg) ? -1e30f : sv;
                    }
#pragma unroll
            for (int mi = 0; mi < 2; ++mi)
#pragma unroll
                for (int j = 0; j < 4; ++j) {
                    float pm = fmaxf(fmaxf(sf[mi][0][j], sf[mi][1][j]),
                                     fmaxf(sf[mi][2][j], sf[mi][3][j]));
#pragma unroll
                    for (int msk = 1; msk <= 8; msk <<= 1)
                        pm = fmaxf(pm, __shfl_xor(pm, msk));
                    const float mnew = fmaxf(mrow[mi][j], pm);
                    const float resc = __expf(mrow[mi][j] - mnew);
                    mrow[mi][j] = mnew;
                    float rsum = 0.f;
#pragma unroll
                    for (int ni = 0; ni < 4; ++ni) {
                        const float p = __expf(sf[mi][ni][j] - mnew);
                        sf[mi][ni][j] = p;
                        rsum += p;
                    }
#pragma unroll
                    for (int msk = 1; msk <= 8; msk <<= 1)
                        rsum += __shfl_xor(rsum, msk);
                    lrow[mi][j] = lrow[mi][j] * resc + rsum;
#pragma unroll
                    for (int di = 0; di < 4; ++di) oacc[mi][di][j] *= resc;
                }
#pragma unroll
            for (int mi = 0; mi < 2; ++mi)
#pragma unroll
                for (int ni = 0; ni < 4; ++ni)
#pragma unroll
                    for (int j = 0; j < 4; ++j) {
                        const float p = sf[mi][ni][j];
                        const int idx = (mi * 16 + lg * 4 + j) * 64 + ni * 16 + lr;
                        bf16 hh, lo2; split2(p, hh, lo2);
                        Psh[w][idx] = hh;
                        Psl[w][idx] = lo2;
                    }
#pragma unroll
            for (int ks = 0; ks < 2; ++ks) {
                bf16x8 pah[2], pal[2];
#pragma unroll
                for (int mi = 0; mi < 2; ++mi) {
                    const int off = (mi * 16 + lr) * 64 + ks * 32 + lg * 8;
                    pah[mi] = *(const bf16x8*)&Psh[w][off];
                    pal[mi] = *(const bf16x8*)&Psl[w][off];
                }
#pragma unroll
                for (int di = 0; di < 4; ++di) {
                    const int off = (di * 16 + lr) * 64 + ks * 32 + lg * 8;
                    const bf16x8 vfh = *(const bf16x8*)&Vsh[off];
                    const bf16x8 vfl = *(const bf16x8*)&Vsl[off];
#pragma unroll
                    for (int mi = 0; mi < 2; ++mi) {
                        mfma16(oacc[mi][di], pah[mi], vfh);
                        mfma16(oacc[mi][di], pah[mi], vfl);
                        mfma16(oacc[mi][di], pal[mi], vfh);
                    }
                }
            }
        }
        __syncthreads();
    }
#pragma unroll
    for (int mi = 0; mi < 2; ++mi)
#pragma unroll
        for (int j = 0; j < 4; ++j) {
            const float inv = 1.0f / lrow[mi][j];
            const int row = qrow0 + mi * 16 + lg * 4 + j;
#pragma unroll
            for (int di = 0; di < 4; ++di) {
                const float f = oacc[mi][di][j] * inv;
                bf16 hh, lo2; split2(f, hh, lo2);
                const size_t idx = (tokbase + row) * DM + h * HD + di * 16 + lr;
                oh[idx] = hh;
                ol[idx] = lo2;
            }
        }
}

// =======================================================================
extern "C" void kernel_launch(void* const* d_in, const int* in_sizes, int n_in,
                              void* d_out, int out_size, void* d_ws, size_t ws_size,
                              hipStream_t stream) {
    const float* x    = (const float*)d_in[0];
    const float* ln1s = (const float*)d_in[2];
    const float* ln1b = (const float*)d_in[3];
    const float* Wq   = (const float*)d_in[4];
    const float* bq   = (const float*)d_in[5];
    const float* Wk   = (const float*)d_in[6];
    const float* bk   = (const float*)d_in[7];
    const float* Wv   = (const float*)d_in[8];
    const float* bv   = (const float*)d_in[9];
    const float* Wo   = (const float*)d_in[10];
    const float* bo   = (const float*)d_in[11];
    const float* ln2s = (const float*)d_in[12];
    const float* ln2b = (const float*)d_in[13];
    const float* W1   = (const float*)d_in[14];
    const float* b1   = (const float*)d_in[15];
    const float* W2   = (const float*)d_in[16];
    const float* b2   = (const float*)d_in[17];
    float* out = (float*)d_out;

    const size_t M1 = (size_t)1024 * 1024;  // 1M elems
    bf16* ws = (bf16*)d_ws;
    // weights (hi planes only now)
    bf16* Wqkv_h = ws;                 // 3M
    bf16* Wo_h   = ws + 6 * M1;
    bf16* W1_h   = ws + 8 * M1;        // 4M
    bf16* W2_h   = ws + 16 * M1;       // 4M
    // activations
    bf16*  xn_h  = ws + 24 * M1;       // 4M
    float* x1    = (float*)(ws + 32 * M1);  // 4M fp32 (8M slots)
    bf16*  q_h   = ws + 40 * M1;
    bf16*  q_l   = ws + 44 * M1;
    bf16*  k_h   = ws + 48 * M1;
    bf16*  k_l   = ws + 52 * M1;
    bf16*  vt_h  = ws + 56 * M1;
    bf16*  vt_l  = ws + 60 * M1;
    bf16*  o_h   = ws + 64 * M1;
    bf16*  o_l   = ws + 68 * M1;       // written by frozen attn (unused downstream)
    // MLP hidden (hi only) overlays q..o region (dead after O-proj)
    bf16*  h_h   = ws + 40 * M1;       // 16M

    const dim3 blk(256);
    transpose_convert_h<<<dim3(32, 32), blk, 0, stream>>>(Wq, Wqkv_h,        1024, 1024);
    transpose_convert_h<<<dim3(32, 32), blk, 0, stream>>>(Wk, Wqkv_h + M1,   1024, 1024);
    transpose_convert_h<<<dim3(32, 32), blk, 0, stream>>>(Wv, Wqkv_h + 2*M1, 1024, 1024);
    transpose_convert_h<<<dim3(32, 32), blk, 0, stream>>>(Wo, Wo_h, 1024, 1024);
    transpose_convert_h<<<dim3(128, 32), blk, 0, stream>>>(W1, W1_h, 1024, 4096);
    transpose_convert_h<<<dim3(32, 128), blk, 0, stream>>>(W2, W2_h, 4096, 1024);

    layernorm_h<<<NTOK, blk, 0, stream>>>(x, ln1s, ln1b, xn_h);

    // fused QKV: plain bf16 x plain bf16 (32KB LDS)
    gemm_bt5b<<<dim3(24, 32), blk, 0, stream>>>(xn_h, Wqkv_h,
        bq, bk, bv, q_h, k_h, vt_h, 4 * M1, NTOK, 3072, 1024);

    attn_kernel<<<512, blk, 0, stream>>>(q_h, q_l, k_h, k_l, vt_h, vt_l, o_h, o_l);

    // O projection + residual: plain bf16 x plain bf16 (launch-site swap to
    // the proven gemm_bt1; Wo-lo term dropped, ~2^-9 relative)
    gemm_bt1<3><<<dim3(8, 32), blk, 0, stream>>>(o_h, Wo_h,
        bo, x, x1, NTOK, 1024, 1024);

    layernorm_h<<<NTOK, blk, 0, stream>>>(x1, ln2s, ln2b, xn_h);

    // MLP up + GELU
    gemm_bt1<4><<<dim3(32, 32), blk, 0, stream>>>(xn_h, W1_h,
        b1, nullptr, h_h, NTOK, DFF, 1024);

    // MLP down + residual -> out
    gemm_bt1<3><<<dim3(8, 32), blk, 0, stream>>>(h_h, W2_h,
        b2, x1, out, NTOK, 1024, DFF);
}